// Round 8
// baseline (2079.779 us; speedup 1.0000x reference)
//
#include <hip/hip_runtime.h>
#include <cstdint>
#include <cstddef>

// ---------------------------------------------------------------------------
// EGT layer, f32.  N nodes (DIM=96, H=32, HD=3), E edges.
// edge_tile_kernel: 64-edge tile per 256-thread block, all row state in LDS,
// matvecs as block-cooperative GEMMs (acc[4][4]/thread) -- no per-lane rows,
// nothing for the compiler to demote to scratch.
// Atomic-free aggregation via CSR bucketing.
// ---------------------------------------------------------------------------

__device__ __forceinline__ float red32(float v) {
    #pragma unroll
    for (int m = 16; m >= 1; m >>= 1) v += __shfl_xor(v, m, 64);
    return v;
}

// ---------------- row LayerNorm over D=96 ----------------
__global__ __launch_bounds__(256) void ln96_kernel(
    const float* __restrict__ x, const float* __restrict__ g,
    const float* __restrict__ b, float* __restrict__ y, int M)
{
    int lane = threadIdx.x & 31;
    int grp  = threadIdx.x >> 5;
    int r = blockIdx.x * 8 + grp;
    if (r >= M) return;
    const float* xr = x + (size_t)r * 96;
    float a0 = xr[lane], a1 = xr[lane + 32], a2 = xr[lane + 64];
    float mu = red32(a0 + a1 + a2) * (1.f / 96.f);
    float d0 = a0 - mu, d1 = a1 - mu, d2 = a2 - mu;
    float var = red32(d0 * d0 + d1 * d1 + d2 * d2) * (1.f / 96.f);
    float rs = rsqrtf(var + 1e-5f);
    float* yr = y + (size_t)r * 96;
    yr[lane]      = d0 * rs * g[lane]      + b[lane];
    yr[lane + 32] = d1 * rs * g[lane + 32] + b[lane + 32];
    yr[lane + 64] = d2 * rs * g[lane + 64] + b[lane + 64];
}

// ---------------- generic small-N GEMM: C[M,*] = A[M,K] @ B[K,*] + bias -----
template<int RELU, int RES>
__global__ __launch_bounds__(192) void gemm_kernel(
    const float* __restrict__ A, int lda,
    const float* __restrict__ B, int ldb,
    const float* __restrict__ bias,
    const float* __restrict__ resid,
    const float* __restrict__ wptr,
    float* __restrict__ C, int ldc, int n0,
    int M, int K)
{
    __shared__ float sA[32 * 68];
    __shared__ float sB[32 * 48];
    const int tid = threadIdx.x;
    const int tx = tid % 12;
    const int ty = tid / 12;
    const int m0 = blockIdx.x * 64;
    const int nb = blockIdx.y * 48;
    float acc[4][4] = {};

    for (int kc = 0; kc < K; kc += 32) {
        for (int idx = tid; idx < 64 * 32; idx += 192) {
            int m = idx >> 5, k = idx & 31;
            int row = m0 + m;
            sA[k * 68 + m] = (row < M) ? A[(size_t)row * lda + kc + k] : 0.f;
        }
        for (int idx = tid; idx < 32 * 48; idx += 192) {
            int k = idx / 48, n = idx - k * 48;
            sB[idx] = B[(size_t)(kc + k) * ldb + nb + n];
        }
        __syncthreads();
        #pragma unroll
        for (int k = 0; k < 32; k++) {
            float4 av = *(const float4*)&sA[k * 68 + ty * 4];
            float4 bv = *(const float4*)&sB[k * 48 + tx * 4];
            float a4[4] = {av.x, av.y, av.z, av.w};
            float b4[4] = {bv.x, bv.y, bv.z, bv.w};
            #pragma unroll
            for (int i = 0; i < 4; i++)
                #pragma unroll
                for (int j = 0; j < 4; j++)
                    acc[i][j] += a4[i] * b4[j];
        }
        __syncthreads();
    }

    float scale = 1.f;
    if (RES) scale = wptr ? (1.f + wptr[0]) : 1.f;
    #pragma unroll
    for (int i = 0; i < 4; i++) {
        int row = m0 + ty * 4 + i;
        if (row >= M) continue;
        #pragma unroll
        for (int j = 0; j < 4; j++) {
            int col = nb + tx * 4 + j;
            float v = acc[i][j] + bias[col];
            if (RELU) v = fmaxf(v, 0.f);
            if (RES) v += scale * resid[(size_t)row * ldc + n0 + col];
            C[(size_t)row * ldc + n0 + col] = v;
        }
    }
}

// ---------------- CSR bucketing ----------------
__global__ __launch_bounds__(256) void count_kernel(
    const int* __restrict__ dst, int* __restrict__ cnt, int E)
{
    int i = blockIdx.x * 256 + threadIdx.x;
    if (i < E) atomicAdd(&cnt[dst[i]], 1);
}

__global__ __launch_bounds__(1024) void scan_kernel(
    const int* __restrict__ cnt, int* __restrict__ off, int* __restrict__ cur, int N)
{
    __shared__ int s[1024];
    const int tid = threadIdx.x;
    const int chunk = (N + 1023) >> 10;
    const int lo = tid * chunk;
    const int hi = min(lo + chunk, N);
    int sum = 0;
    for (int i = lo; i < hi; i++) sum += cnt[i];
    s[tid] = sum;
    __syncthreads();
    for (int d = 1; d < 1024; d <<= 1) {
        int v = (tid >= d) ? s[tid - d] : 0;
        __syncthreads();
        s[tid] += v;
        __syncthreads();
    }
    int base = (tid == 0) ? 0 : s[tid - 1];
    for (int i = lo; i < hi; i++) {
        off[i] = base; cur[i] = base;
        base += cnt[i];
    }
}

__global__ __launch_bounds__(256) void scatter_kernel(
    const int* __restrict__ dst, int* __restrict__ cur,
    int* __restrict__ eidx, int E)
{
    int i = blockIdx.x * 256 + threadIdx.x;
    if (i < E) {
        int p = atomicAdd(&cur[dst[i]], 1);
        eidx[p] = i;
    }
}

// ---------------- score: qk[e][h] = 0.5 * <k[src][h], q[dst][h]> -----------
__global__ __launch_bounds__(256) void score_kernel(
    const float* __restrict__ qkv, const int* __restrict__ src,
    const int* __restrict__ dst, float* __restrict__ qk, int E)
{
    __shared__ float sQ[8][96], sK[8][96];
    const int lane = threadIdx.x & 31;
    const int grp  = threadIdx.x >> 5;
    long long e = (long long)blockIdx.x * 8 + grp;
    if (e >= E) return;
    int sn = src[e], dn = dst[e];
    if (lane < 24) {
        float4 qv = *(const float4*)(qkv + (size_t)dn * 288 + lane * 4);
        float4 kv = *(const float4*)(qkv + (size_t)sn * 288 + 96 + lane * 4);
        *(float4*)&sQ[grp][lane * 4] = qv;
        *(float4*)&sK[grp][lane * 4] = kv;
    }
    __builtin_amdgcn_wave_barrier();
    float q0 = sQ[grp][lane * 3], q1 = sQ[grp][lane * 3 + 1], q2 = sQ[grp][lane * 3 + 2];
    float k0 = sK[grp][lane * 3], k1 = sK[grp][lane * 3 + 1], k2 = sK[grp][lane * 3 + 2];
    qk[e * 32 + lane] = (k0 * q0 + k1 * q1 + k2 * q2) * 0.5f;
}

// ---------------- edge tile kernel: 64 edges per 256-thread block ----------
// exve layout: [E][64] = {ex[0..32), ve[32..64)}; gather multiplies ex*ve.
__global__ __launch_bounds__(256) void edge_tile_kernel(
    const float* __restrict__ edge, const float* __restrict__ qk,
    const float* __restrict__ We, const float* __restrict__ be,
    const float* __restrict__ Wb, const float* __restrict__ bb,
    const float* __restrict__ Wf0, const float* __restrict__ bf0,
    const float* __restrict__ Wf1, const float* __restrict__ bf1,
    const float* __restrict__ ge0, const float* __restrict__ be0,
    const float* __restrict__ ge1, const float* __restrict__ be1,
    float* __restrict__ exve, float* __restrict__ eout, int E)
{
    __shared__ float bufA[64 * 36];   // ev rows -> er rows        [64][36]
    __shared__ float bufB[32 * 72];   // ew^T then en^T            [k][m]
    __shared__ float bufW[32 * 72];   // [Wb|We] then Wf0          [k][n]
    __shared__ float bufW2[32 * 72];  // Wf1^T                     [n][k]
    __shared__ float bufF[64 * 76];   // F rows (relu'd)           [64][76]

    const int tid = threadIdx.x;
    const long long e0 = (long long)blockIdx.x * 64;
    const int tx = tid & 15, ty = tid >> 4;

    // ---- S1: stage ev, Wb|We, Wf1^T ----
    #pragma unroll
    for (int r = 0; r < 2; r++) {
        int idx4 = tid + 256 * r;                 // 512 float4 of edge tile
        int row = idx4 >> 3, c4 = (idx4 & 7) * 4;
        long long e = e0 + row;
        float4 v = make_float4(0.f, 0.f, 0.f, 0.f);
        if (e < E) v = *(const float4*)(edge + e * 32 + c4);
        *(float4*)&bufA[row * 36 + c4] = v;
    }
    {
        int k = tid >> 3, c4 = (tid & 7) * 4;     // 256 float4 each
        *(float4*)&bufW[k * 72 + c4]      = *(const float4*)(Wb + k * 32 + c4);
        *(float4*)&bufW[k * 72 + 32 + c4] = *(const float4*)(We + k * 32 + c4);
    }
    #pragma unroll
    for (int r = 0; r < 2; r++) {
        int idx4 = tid + 256 * r;                 // 512 float4 of Wf1 [64][32]
        int k = idx4 >> 3, n4 = (idx4 & 7) * 4;
        float4 v = *(const float4*)(Wf1 + k * 32 + n4);
        bufW2[(n4 + 0) * 72 + k] = v.x;
        bufW2[(n4 + 1) * 72 + k] = v.y;
        bufW2[(n4 + 2) * 72 + k] = v.z;
        bufW2[(n4 + 3) * 72 + k] = v.w;
    }
    __syncthreads();

    // ---- S2: LN1 (wave-parallel: lane owns row-quarter) -> ew^T in bufB ----
    {
        const int l = tid & 63, w = tid >> 6;
        const int row = 16 * w + (l & 15);
        const int q = l >> 4;
        float x[8];
        *(float4*)&x[0] = *(float4*)&bufA[row * 36 + 8 * q];
        *(float4*)&x[4] = *(float4*)&bufA[row * 36 + 8 * q + 4];
        float s = x[0] + x[1] + x[2] + x[3] + x[4] + x[5] + x[6] + x[7];
        s += __shfl_xor(s, 16, 64); s += __shfl_xor(s, 32, 64);
        float mu = s * (1.f / 32.f);
        float v2 = 0.f;
        #pragma unroll
        for (int i = 0; i < 8; i++) { float d = x[i] - mu; v2 += d * d; }
        v2 += __shfl_xor(v2, 16, 64); v2 += __shfl_xor(v2, 32, 64);
        float rs = rsqrtf(v2 * (1.f / 32.f) + 1e-5f);
        float4 g1 = *(const float4*)(ge0 + 8 * q), g2 = *(const float4*)(ge0 + 8 * q + 4);
        float4 b1 = *(const float4*)(be0 + 8 * q), b2 = *(const float4*)(be0 + 8 * q + 4);
        float gg[8] = {g1.x, g1.y, g1.z, g1.w, g2.x, g2.y, g2.z, g2.w};
        float bs[8] = {b1.x, b1.y, b1.z, b1.w, b2.x, b2.y, b2.z, b2.w};
        #pragma unroll
        for (int i = 0; i < 8; i++)
            bufB[(8 * q + i) * 72 + row] = (x[i] - mu) * rs * gg[i] + bs[i];
    }
    __syncthreads();

    // ---- S3: GEMM1  [64 edges][64 = sc|veh] = ew @ [Wb|We] ----
    float acc[4][4] = {};
    #pragma unroll
    for (int k = 0; k < 32; k++) {
        float4 av = *(float4*)&bufB[k * 72 + ty * 4];
        float4 bv = *(float4*)&bufW[k * 72 + tx * 4];
        float a4[4] = {av.x, av.y, av.z, av.w};
        float b4[4] = {bv.x, bv.y, bv.z, bv.w};
        #pragma unroll
        for (int i = 0; i < 4; i++)
            #pragma unroll
            for (int j = 0; j < 4; j++)
                acc[i][j] += a4[i] * b4[j];
    }
    __syncthreads();

    // ---- S4: epilogue1 (exp + exve stores + er in bufA) + stage Wf0 ----
    if (tx < 8) {
        int c = tx * 4;
        float4 bbv = *(const float4*)(bb + c);
        #pragma unroll
        for (int i = 0; i < 4; i++) {
            int rowi = ty * 4 + i;
            long long e = e0 + rowi;
            float4 qv = make_float4(0.f, 0.f, 0.f, 0.f);
            if (e < E) qv = *(const float4*)(qk + e * 32 + c);
            float s0 = acc[i][0] + qv.x + bbv.x;
            float s1 = acc[i][1] + qv.y + bbv.y;
            float s2 = acc[i][2] + qv.z + bbv.z;
            float s3 = acc[i][3] + qv.w + bbv.w;
            float4 exv = make_float4(__expf(s0), __expf(s1), __expf(s2), __expf(s3));
            if (e < E) *(float4*)(exve + e * 64 + c) = exv;
            float4 evv = *(float4*)&bufA[rowi * 36 + c];
            float4 er  = make_float4(s0 + evv.x, s1 + evv.y, s2 + evv.z, s3 + evv.w);
            *(float4*)&bufA[rowi * 36 + c] = er;
        }
    } else {
        int c = (tx - 8) * 4;
        float4 bev = *(const float4*)(be + c);
        #pragma unroll
        for (int i = 0; i < 4; i++) {
            int rowi = ty * 4 + i;
            long long e = e0 + rowi;
            float4 ve = make_float4(acc[i][0] + bev.x, acc[i][1] + bev.y,
                                    acc[i][2] + bev.z, acc[i][3] + bev.w);
            if (e < E) *(float4*)(exve + e * 64 + 32 + c) = ve;
        }
    }
    #pragma unroll
    for (int r = 0; r < 2; r++) {
        int idx4 = tid + 256 * r;                 // 512 float4 of Wf0 [32][64]
        int k = idx4 >> 4, c4 = (idx4 & 15) * 4;
        *(float4*)&bufW[k * 72 + c4] = *(const float4*)(Wf0 + k * 64 + c4);
    }
    __syncthreads();

    // ---- S5: LN2 on er rows -> en^T in bufB ----
    {
        const int l = tid & 63, w = tid >> 6;
        const int row = 16 * w + (l & 15);
        const int q = l >> 4;
        float x[8];
        *(float4*)&x[0] = *(float4*)&bufA[row * 36 + 8 * q];
        *(float4*)&x[4] = *(float4*)&bufA[row * 36 + 8 * q + 4];
        float s = x[0] + x[1] + x[2] + x[3] + x[4] + x[5] + x[6] + x[7];
        s += __shfl_xor(s, 16, 64); s += __shfl_xor(s, 32, 64);
        float mu = s * (1.f / 32.f);
        float v2 = 0.f;
        #pragma unroll
        for (int i = 0; i < 8; i++) { float d = x[i] - mu; v2 += d * d; }
        v2 += __shfl_xor(v2, 16, 64); v2 += __shfl_xor(v2, 32, 64);
        float rs = rsqrtf(v2 * (1.f / 32.f) + 1e-5f);
        float4 g1 = *(const float4*)(ge1 + 8 * q), g2 = *(const float4*)(ge1 + 8 * q + 4);
        float4 b1 = *(const float4*)(be1 + 8 * q), b2 = *(const float4*)(be1 + 8 * q + 4);
        float gg[8] = {g1.x, g1.y, g1.z, g1.w, g2.x, g2.y, g2.z, g2.w};
        float bs[8] = {b1.x, b1.y, b1.z, b1.w, b2.x, b2.y, b2.z, b2.w};
        #pragma unroll
        for (int i = 0; i < 8; i++)
            bufB[(8 * q + i) * 72 + row] = (x[i] - mu) * rs * gg[i] + bs[i];
    }
    __syncthreads();

    // ---- S6: GEMM2  F[64][64] = en @ Wf0, relu, -> bufF rows ----
    {
        float acc2[4][4] = {};
        #pragma unroll
        for (int k = 0; k < 32; k++) {
            float4 av = *(float4*)&bufB[k * 72 + ty * 4];
            float4 bv = *(float4*)&bufW[k * 72 + tx * 4];
            float a4[4] = {av.x, av.y, av.z, av.w};
            float b4[4] = {bv.x, bv.y, bv.z, bv.w};
            #pragma unroll
            for (int i = 0; i < 4; i++)
                #pragma unroll
                for (int j = 0; j < 4; j++)
                    acc2[i][j] += a4[i] * b4[j];
        }
        float4 bf0v = *(const float4*)(bf0 + tx * 4);
        #pragma unroll
        for (int i = 0; i < 4; i++) {
            float4 f;
            f.x = fmaxf(acc2[i][0] + bf0v.x, 0.f);
            f.y = fmaxf(acc2[i][1] + bf0v.y, 0.f);
            f.z = fmaxf(acc2[i][2] + bf0v.z, 0.f);
            f.w = fmaxf(acc2[i][3] + bf0v.w, 0.f);
            *(float4*)&bufF[(ty * 4 + i) * 76 + tx * 4] = f;
        }
    }
    __syncthreads();

    // ---- S7: GEMM3  out[64][32] = F @ Wf1 + er + bf1 ----
    {
        float a2[4][2] = {};
        #pragma unroll
        for (int kc = 0; kc < 64; kc += 4) {
            float4 b0 = *(float4*)&bufW2[(tx * 2 + 0) * 72 + kc];
            float4 b1 = *(float4*)&bufW2[(tx * 2 + 1) * 72 + kc];
            #pragma unroll
            for (int i = 0; i < 4; i++) {
                float4 aa = *(float4*)&bufF[(ty * 4 + i) * 76 + kc];
                a2[i][0] += aa.x * b0.x + aa.y * b0.y + aa.z * b0.z + aa.w * b0.w;
                a2[i][1] += aa.x * b1.x + aa.y * b1.y + aa.z * b1.z + aa.w * b1.w;
            }
        }
        int c = tx * 2;
        float f1a = bf1[c], f1b = bf1[c + 1];
        #pragma unroll
        for (int i = 0; i < 4; i++) {
            int rowi = ty * 4 + i;
            long long e = e0 + rowi;
            float era = bufA[rowi * 36 + c], erb = bufA[rowi * 36 + c + 1];
            float o0 = a2[i][0] + era + f1a;
            float o1 = a2[i][1] + erb + f1b;
            if (e < E) {
                float2 st; st.x = o0; st.y = o1;
                *(float2*)(eout + e * 32 + c) = st;
            }
        }
    }
}

// ---------------- gather: one wave per node, halves process alt. edges -----
__global__ __launch_bounds__(256) void gather_kernel(
    const float* __restrict__ exve, const float* __restrict__ qkv,
    const int* __restrict__ src, const int* __restrict__ eidx,
    const int* __restrict__ off, const int* __restrict__ cnt,
    float* __restrict__ agg, int N)
{
    __shared__ float sV[4][2][96];
    __shared__ float sE[4][2][64];
    const int wave = threadIdx.x >> 6;
    const int lane = threadIdx.x & 63;
    const int head = lane & 31;
    const int half = lane >> 5;
    int n = blockIdx.x * 4 + wave;
    if (n >= N) return;
    const int o = off[n], d = cnt[n];
    float a0 = 0.f, a1 = 0.f, a2 = 0.f, a3 = 0.f, den = 0.f;
    for (int i = half; i < d; i += 2) {
        int e = eidx[o + i];
        int sn = src[e];
        const float* vr = qkv + (size_t)sn * 288 + 192;
        const float* er = exve + (size_t)e * 64;
        if (head < 24) {
            *(float4*)&sV[wave][half][head * 4] = *(const float4*)(vr + head * 4);
        } else {
            int j = head - 24;
            *(float4*)&sE[wave][half][j * 8]     = *(const float4*)(er + j * 8);
            *(float4*)&sE[wave][half][j * 8 + 4] = *(const float4*)(er + j * 8 + 4);
        }
        __builtin_amdgcn_wave_barrier();
        float ex = sE[wave][half][head];
        float vv = sE[wave][half][32 + head];
        a0 += ex * sV[wave][half][head * 3];
        a1 += ex * sV[wave][half][head * 3 + 1];
        a2 += ex * sV[wave][half][head * 3 + 2];
        a3 += ex * vv;
        den += ex;
        __builtin_amdgcn_wave_barrier();
    }
    a0 += __shfl_xor(a0, 32, 64);
    a1 += __shfl_xor(a1, 32, 64);
    a2 += __shfl_xor(a2, 32, 64);
    a3 += __shfl_xor(a3, 32, 64);
    den += __shfl_xor(den, 32, 64);
    if (half == 0) {
        float sc = (d > 0) ? 1.f / den : 0.f;
        float* ap = agg + (size_t)n * 128 + head * 4;
        ap[0] = a0 * sc; ap[1] = a1 * sc; ap[2] = a2 * sc; ap[3] = a3 * sc;
    }
}

// ---------------------------------------------------------------------------
extern "C" void kernel_launch(void* const* d_in, const int* in_sizes, int n_in,
                              void* d_out, int out_size, void* d_ws, size_t ws_size,
                              hipStream_t stream)
{
    (void)n_in; (void)out_size; (void)ws_size;
    const float* feat = (const float*)d_in[0];
    const float* edge = (const float*)d_in[1];
    const float* Wq   = (const float*)d_in[2];
    const float* bq   = (const float*)d_in[3];
    const float* Wk   = (const float*)d_in[4];
    const float* bk   = (const float*)d_in[5];
    const float* Wv   = (const float*)d_in[6];
    const float* bv   = (const float*)d_in[7];
    const float* We   = (const float*)d_in[8];
    const float* be   = (const float*)d_in[9];
    const float* Wb   = (const float*)d_in[10];
    const float* bb   = (const float*)d_in[11];
    const float* Wvv  = (const float*)d_in[12];
    const float* bvv  = (const float*)d_in[13];
    const float* Wf0  = (const float*)d_in[14];
    const float* bf0  = (const float*)d_in[15];
    const float* Wf1  = (const float*)d_in[16];
    const float* bf1  = (const float*)d_in[17];
    const float* Wm0  = (const float*)d_in[18];
    const float* bm0  = (const float*)d_in[19];
    const float* Wm1  = (const float*)d_in[20];
    const float* bm1  = (const float*)d_in[21];
    const float* g_n0 = (const float*)d_in[22];
    const float* b_n0 = (const float*)d_in[23];
    const float* g_e0 = (const float*)d_in[24];
    const float* b_e0 = (const float*)d_in[25];
    const float* g_e1 = (const float*)d_in[26];
    const float* b_e1 = (const float*)d_in[27];
    const float* g_m  = (const float*)d_in[28];
    const float* b_m  = (const float*)d_in[29];
    const float* wsc  = (const float*)d_in[30];
    const int*   src  = (const int*)d_in[31];
    const int*   dst  = (const int*)d_in[32];

    const int N = in_sizes[0] / 96;
    const int E = in_sizes[1] / 32;

    float* ws    = (float*)d_ws;
    float* qkv   = ws;                                  // N*288
    float* agg   = qkv + (size_t)N * 288;               // N*128
    float* h0    = agg + (size_t)N * 128;               // N*96 (h0, later hn)
    float* hp    = h0 + (size_t)N * 96;                 // N*96
    float* exve  = hp + (size_t)N * 96;                 // E*64 = {ex|ve}
    int*   eidx  = (int*)(exve + (size_t)E * 64);       // E
    int*   cnt   = eidx + E;                            // N
    int*   offv  = cnt + N;                             // N
    int*   cur   = offv + N;                            // N
    float* tbuf  = ws;                                  // N*192, reuses qkv late
    float* hout  = (float*)d_out;
    float* eoutp = (float*)d_out + (size_t)N * 96;      // also hosts qk scores

    hipMemsetAsync(cnt, 0, (size_t)N * sizeof(int), stream);

    const int mt = (N + 63) / 64;
    const int et = (E + 255) / 256;

    // CSR bucketing (independent of node-side work)
    count_kernel<<<et, 256, 0, stream>>>(dst, cnt, E);
    scan_kernel<<<1, 1024, 0, stream>>>(cnt, offv, cur, N);
    scatter_kernel<<<et, 256, 0, stream>>>(dst, cur, eidx, E);

    // node side: h0 = LN(feat); qkv = h0 @ [Wq|Wk|Wv]
    ln96_kernel<<<(N + 7) / 8, 256, 0, stream>>>(feat, g_n0, b_n0, h0, N);
    gemm_kernel<0,0><<<dim3(mt, 2), 192, 0, stream>>>(h0, 96, Wq, 96, bq, nullptr, nullptr, qkv, 288, 0,   N, 96);
    gemm_kernel<0,0><<<dim3(mt, 2), 192, 0, stream>>>(h0, 96, Wk, 96, bk, nullptr, nullptr, qkv, 288, 96,  N, 96);
    gemm_kernel<0,0><<<dim3(mt, 2), 192, 0, stream>>>(h0, 96, Wv, 96, bv, nullptr, nullptr, qkv, 288, 192, N, 96);

    // scores -> eoutp region (qk buffer); edge tile pass consumes + overwrites
    score_kernel<<<(E + 7) / 8, 256, 0, stream>>>(qkv, src, dst, eoutp, E);
    edge_tile_kernel<<<(E + 63) / 64, 256, 0, stream>>>(edge, eoutp,
                                             We, be, Wb, bb, Wf0, bf0, Wf1, bf1,
                                             g_e0, b_e0, g_e1, b_e1,
                                             exve, eoutp, E);

    // gather per node -> normalized agg[N,128]
    gather_kernel<<<(N + 3) / 4, 256, 0, stream>>>(exve, qkv, src, eidx, offv, cnt, agg, N);

    // h_pre = feat*(1+w) + agg @ Wvv + bvv
    gemm_kernel<0,1><<<dim3(mt, 2), 192, 0, stream>>>(agg, 128, Wvv, 96, bvv, feat, wsc, hp, 96, 0, N, 128);
    // hn = LN(h_pre)
    ln96_kernel<<<(N + 7) / 8, 256, 0, stream>>>(hp, g_m, b_m, h0, N);
    // t = relu(hn @ Wm0 + bm0)
    gemm_kernel<1,0><<<dim3(mt, 4), 192, 0, stream>>>(h0, 96, Wm0, 192, bm0, nullptr, nullptr, tbuf, 192, 0, N, 96);
    // h_out = h_pre + t @ Wm1 + bm1
    gemm_kernel<0,1><<<dim3(mt, 2), 192, 0, stream>>>(tbuf, 192, Wm1, 96, bm1, hp, nullptr, hout, 96, 0, N, 192);
}

// Round 9
// 1915.573 us; speedup vs baseline: 1.0857x; 1.0857x over previous
//
#include <hip/hip_runtime.h>
#include <cstdint>
#include <cstddef>

// ---------------------------------------------------------------------------
// EGT layer, f32.  N nodes (DIM=96, H=32, HD=3), E edges.
// edge_tile_kernel: 64-edge tile per 256-thread block, all row state in LDS,
// row-major everywhere (no transpose writes -> no bank conflicts), GEMMs read
// A and B rows as float4 with k chunked by 4.  52.5 KB LDS -> 3 blocks/CU.
// Atomic-free aggregation via CSR bucketing.
// ---------------------------------------------------------------------------

__device__ __forceinline__ float red32(float v) {
    #pragma unroll
    for (int m = 16; m >= 1; m >>= 1) v += __shfl_xor(v, m, 64);
    return v;
}

// ---------------- row LayerNorm over D=96 ----------------
__global__ __launch_bounds__(256) void ln96_kernel(
    const float* __restrict__ x, const float* __restrict__ g,
    const float* __restrict__ b, float* __restrict__ y, int M)
{
    int lane = threadIdx.x & 31;
    int grp  = threadIdx.x >> 5;
    int r = blockIdx.x * 8 + grp;
    if (r >= M) return;
    const float* xr = x + (size_t)r * 96;
    float a0 = xr[lane], a1 = xr[lane + 32], a2 = xr[lane + 64];
    float mu = red32(a0 + a1 + a2) * (1.f / 96.f);
    float d0 = a0 - mu, d1 = a1 - mu, d2 = a2 - mu;
    float var = red32(d0 * d0 + d1 * d1 + d2 * d2) * (1.f / 96.f);
    float rs = rsqrtf(var + 1e-5f);
    float* yr = y + (size_t)r * 96;
    yr[lane]      = d0 * rs * g[lane]      + b[lane];
    yr[lane + 32] = d1 * rs * g[lane + 32] + b[lane + 32];
    yr[lane + 64] = d2 * rs * g[lane + 64] + b[lane + 64];
}

// ---------------- generic small-N GEMM: C[M,*] = A[M,K] @ B[K,*] + bias -----
template<int RELU, int RES>
__global__ __launch_bounds__(192) void gemm_kernel(
    const float* __restrict__ A, int lda,
    const float* __restrict__ B, int ldb,
    const float* __restrict__ bias,
    const float* __restrict__ resid,
    const float* __restrict__ wptr,
    float* __restrict__ C, int ldc, int n0,
    int M, int K)
{
    __shared__ float sA[32 * 68];
    __shared__ float sB[32 * 48];
    const int tid = threadIdx.x;
    const int tx = tid % 12;
    const int ty = tid / 12;
    const int m0 = blockIdx.x * 64;
    const int nb = blockIdx.y * 48;
    float acc[4][4] = {};

    for (int kc = 0; kc < K; kc += 32) {
        for (int idx = tid; idx < 64 * 32; idx += 192) {
            int m = idx >> 5, k = idx & 31;
            int row = m0 + m;
            sA[k * 68 + m] = (row < M) ? A[(size_t)row * lda + kc + k] : 0.f;
        }
        for (int idx = tid; idx < 32 * 48; idx += 192) {
            int k = idx / 48, n = idx - k * 48;
            sB[idx] = B[(size_t)(kc + k) * ldb + nb + n];
        }
        __syncthreads();
        #pragma unroll
        for (int k = 0; k < 32; k++) {
            float4 av = *(const float4*)&sA[k * 68 + ty * 4];
            float4 bv = *(const float4*)&sB[k * 48 + tx * 4];
            float a4[4] = {av.x, av.y, av.z, av.w};
            float b4[4] = {bv.x, bv.y, bv.z, bv.w};
            #pragma unroll
            for (int i = 0; i < 4; i++)
                #pragma unroll
                for (int j = 0; j < 4; j++)
                    acc[i][j] += a4[i] * b4[j];
        }
        __syncthreads();
    }

    float scale = 1.f;
    if (RES) scale = wptr ? (1.f + wptr[0]) : 1.f;
    #pragma unroll
    for (int i = 0; i < 4; i++) {
        int row = m0 + ty * 4 + i;
        if (row >= M) continue;
        #pragma unroll
        for (int j = 0; j < 4; j++) {
            int col = nb + tx * 4 + j;
            float v = acc[i][j] + bias[col];
            if (RELU) v = fmaxf(v, 0.f);
            if (RES) v += scale * resid[(size_t)row * ldc + n0 + col];
            C[(size_t)row * ldc + n0 + col] = v;
        }
    }
}

// ---------------- CSR bucketing ----------------
__global__ __launch_bounds__(256) void count_kernel(
    const int* __restrict__ dst, int* __restrict__ cnt, int E)
{
    int i = blockIdx.x * 256 + threadIdx.x;
    if (i < E) atomicAdd(&cnt[dst[i]], 1);
}

__global__ __launch_bounds__(1024) void scan_kernel(
    const int* __restrict__ cnt, int* __restrict__ off, int* __restrict__ cur, int N)
{
    __shared__ int s[1024];
    const int tid = threadIdx.x;
    const int chunk = (N + 1023) >> 10;
    const int lo = tid * chunk;
    const int hi = min(lo + chunk, N);
    int sum = 0;
    for (int i = lo; i < hi; i++) sum += cnt[i];
    s[tid] = sum;
    __syncthreads();
    for (int d = 1; d < 1024; d <<= 1) {
        int v = (tid >= d) ? s[tid - d] : 0;
        __syncthreads();
        s[tid] += v;
        __syncthreads();
    }
    int base = (tid == 0) ? 0 : s[tid - 1];
    for (int i = lo; i < hi; i++) {
        off[i] = base; cur[i] = base;
        base += cnt[i];
    }
}

__global__ __launch_bounds__(256) void scatter_kernel(
    const int* __restrict__ dst, int* __restrict__ cur,
    int* __restrict__ eidx, int E)
{
    int i = blockIdx.x * 256 + threadIdx.x;
    if (i < E) {
        int p = atomicAdd(&cur[dst[i]], 1);
        eidx[p] = i;
    }
}

// ---------------- score: qk[e][h] = 0.5 * <k[src][h], q[dst][h]> -----------
__global__ __launch_bounds__(256) void score_kernel(
    const float* __restrict__ qkv, const int* __restrict__ src,
    const int* __restrict__ dst, float* __restrict__ qk, int E)
{
    __shared__ float sQ[8][96], sK[8][96];
    const int lane = threadIdx.x & 31;
    const int grp  = threadIdx.x >> 5;
    long long e = (long long)blockIdx.x * 8 + grp;
    if (e >= E) return;
    int sn = src[e], dn = dst[e];
    if (lane < 24) {
        float4 qv = *(const float4*)(qkv + (size_t)dn * 288 + lane * 4);
        float4 kv = *(const float4*)(qkv + (size_t)sn * 288 + 96 + lane * 4);
        *(float4*)&sQ[grp][lane * 4] = qv;
        *(float4*)&sK[grp][lane * 4] = kv;
    }
    __builtin_amdgcn_wave_barrier();
    float q0 = sQ[grp][lane * 3], q1 = sQ[grp][lane * 3 + 1], q2 = sQ[grp][lane * 3 + 2];
    float k0 = sK[grp][lane * 3], k1 = sK[grp][lane * 3 + 1], k2 = sK[grp][lane * 3 + 2];
    qk[e * 32 + lane] = (k0 * q0 + k1 * q1 + k2 * q2) * 0.5f;
}

// ---------------- edge tile kernel: 64 edges per 256-thread block ----------
// exve layout: [E][64] = {ex[0..32), ve[32..64)}; gather multiplies ex*ve.
__global__ __launch_bounds__(256) void edge_tile_kernel(
    const float* __restrict__ edge, const float* __restrict__ qk,
    const float* __restrict__ We, const float* __restrict__ be,
    const float* __restrict__ Wb, const float* __restrict__ bb,
    const float* __restrict__ Wf0, const float* __restrict__ bf0,
    const float* __restrict__ Wf1, const float* __restrict__ bf1,
    const float* __restrict__ ge0, const float* __restrict__ be0,
    const float* __restrict__ ge1, const float* __restrict__ be1,
    float* __restrict__ exve, float* __restrict__ eout, int E)
{
    __shared__ float sEV[64 * 36];   // ev rows -> er rows
    __shared__ float sN [64 * 36];   // ew rows -> en rows
    __shared__ float sW [32 * 68];   // Wb|We -> Wf0 (rows)
    __shared__ float sW1[64 * 36];   // Wf1 rows
    __shared__ float sF [64 * 68];   // F rows (relu'd)
    // total 52.5 KB -> 3 blocks/CU

    const int tid = threadIdx.x;
    const long long e0 = (long long)blockIdx.x * 64;
    const int tx = tid & 15, ty = tid >> 4;

    // ---- prefetch qk tile into registers (consumed in S4, avoids stall) ----
    float4 qpre[4];
    if (tx < 8) {
        #pragma unroll
        for (int i = 0; i < 4; i++) {
            long long e = e0 + ty * 4 + i;
            qpre[i] = make_float4(0.f, 0.f, 0.f, 0.f);
            if (e < E) qpre[i] = *(const float4*)(qk + e * 32 + tx * 4);
        }
    }

    // ---- S1: stage ev rows, Wb|We rows, Wf1 rows ----
    #pragma unroll
    for (int r = 0; r < 2; r++) {
        int idx4 = tid + 256 * r;
        int row = idx4 >> 3, c4 = (idx4 & 7) * 4;
        long long e = e0 + row;
        float4 v = make_float4(0.f, 0.f, 0.f, 0.f);
        if (e < E) v = *(const float4*)(edge + e * 32 + c4);
        *(float4*)&sEV[row * 36 + c4] = v;
    }
    {
        int k = tid >> 3, c4 = (tid & 7) * 4;
        *(float4*)&sW[k * 68 + c4]      = *(const float4*)(Wb + k * 32 + c4);
        *(float4*)&sW[k * 68 + 32 + c4] = *(const float4*)(We + k * 32 + c4);
    }
    #pragma unroll
    for (int r = 0; r < 2; r++) {
        int idx4 = tid + 256 * r;
        int k = idx4 >> 3, c4 = (idx4 & 7) * 4;
        *(float4*)&sW1[k * 36 + c4] = *(const float4*)(Wf1 + k * 32 + c4);
    }
    __syncthreads();

    // ---- S2: LN1 -> ew ROWS in sN (no transpose) ----
    {
        const int l = tid & 63, w = tid >> 6;
        const int row = 16 * w + (l & 15);
        const int q = l >> 4;
        float x[8];
        *(float4*)&x[0] = *(float4*)&sEV[row * 36 + 8 * q];
        *(float4*)&x[4] = *(float4*)&sEV[row * 36 + 8 * q + 4];
        float s = x[0] + x[1] + x[2] + x[3] + x[4] + x[5] + x[6] + x[7];
        s += __shfl_xor(s, 16, 64); s += __shfl_xor(s, 32, 64);
        float mu = s * (1.f / 32.f);
        float v2 = 0.f;
        #pragma unroll
        for (int i = 0; i < 8; i++) { float d = x[i] - mu; v2 += d * d; }
        v2 += __shfl_xor(v2, 16, 64); v2 += __shfl_xor(v2, 32, 64);
        float rs = rsqrtf(v2 * (1.f / 32.f) + 1e-5f);
        float4 g1 = *(const float4*)(ge0 + 8 * q), g2 = *(const float4*)(ge0 + 8 * q + 4);
        float4 b1 = *(const float4*)(be0 + 8 * q), b2 = *(const float4*)(be0 + 8 * q + 4);
        float4 y0, y1;
        y0.x = (x[0] - mu) * rs * g1.x + b1.x;
        y0.y = (x[1] - mu) * rs * g1.y + b1.y;
        y0.z = (x[2] - mu) * rs * g1.z + b1.z;
        y0.w = (x[3] - mu) * rs * g1.w + b1.w;
        y1.x = (x[4] - mu) * rs * g2.x + b2.x;
        y1.y = (x[5] - mu) * rs * g2.y + b2.y;
        y1.z = (x[6] - mu) * rs * g2.z + b2.z;
        y1.w = (x[7] - mu) * rs * g2.w + b2.w;
        *(float4*)&sN[row * 36 + 8 * q]     = y0;
        *(float4*)&sN[row * 36 + 8 * q + 4] = y1;
    }
    __syncthreads();

    // ---- S3: GEMM1  [64][64 = sc|veh] = ew @ [Wb|We], k chunks of 4 ----
    float acc[4][4] = {};
    #pragma unroll
    for (int kc = 0; kc < 32; kc += 4) {
        float4 b0 = *(float4*)&sW[(kc + 0) * 68 + tx * 4];
        float4 b1 = *(float4*)&sW[(kc + 1) * 68 + tx * 4];
        float4 b2 = *(float4*)&sW[(kc + 2) * 68 + tx * 4];
        float4 b3 = *(float4*)&sW[(kc + 3) * 68 + tx * 4];
        #pragma unroll
        for (int i = 0; i < 4; i++) {
            float4 a = *(float4*)&sN[(ty * 4 + i) * 36 + kc];
            acc[i][0] += a.x * b0.x + a.y * b1.x + a.z * b2.x + a.w * b3.x;
            acc[i][1] += a.x * b0.y + a.y * b1.y + a.z * b2.y + a.w * b3.y;
            acc[i][2] += a.x * b0.z + a.y * b1.z + a.z * b2.z + a.w * b3.z;
            acc[i][3] += a.x * b0.w + a.y * b1.w + a.z * b2.w + a.w * b3.w;
        }
    }
    __syncthreads();

    // ---- S4: epilogue1 (exp + exve stores + er into sEV) + restage Wf0 ----
    if (tx < 8) {
        int c = tx * 4;
        float4 bbv = *(const float4*)(bb + c);
        #pragma unroll
        for (int i = 0; i < 4; i++) {
            int rowi = ty * 4 + i;
            long long e = e0 + rowi;
            float s0 = acc[i][0] + qpre[i].x + bbv.x;
            float s1 = acc[i][1] + qpre[i].y + bbv.y;
            float s2 = acc[i][2] + qpre[i].z + bbv.z;
            float s3 = acc[i][3] + qpre[i].w + bbv.w;
            if (e < E) {
                float4 exv = make_float4(__expf(s0), __expf(s1), __expf(s2), __expf(s3));
                *(float4*)(exve + e * 64 + c) = exv;
            }
            float4 evv = *(float4*)&sEV[rowi * 36 + c];
            float4 er  = make_float4(s0 + evv.x, s1 + evv.y, s2 + evv.z, s3 + evv.w);
            *(float4*)&sEV[rowi * 36 + c] = er;
        }
    } else {
        int c = (tx - 8) * 4;
        float4 bev = *(const float4*)(be + c);
        #pragma unroll
        for (int i = 0; i < 4; i++) {
            long long e = e0 + ty * 4 + i;
            if (e < E) {
                float4 ve = make_float4(acc[i][0] + bev.x, acc[i][1] + bev.y,
                                        acc[i][2] + bev.z, acc[i][3] + bev.w);
                *(float4*)(exve + e * 64 + 32 + c) = ve;
            }
        }
    }
    #pragma unroll
    for (int r = 0; r < 2; r++) {
        int idx4 = tid + 256 * r;
        int k = idx4 >> 4, c4 = (idx4 & 15) * 4;
        *(float4*)&sW[k * 68 + c4] = *(const float4*)(Wf0 + k * 64 + c4);
    }
    __syncthreads();

    // ---- S5: LN2 on er rows -> en ROWS in sN ----
    {
        const int l = tid & 63, w = tid >> 6;
        const int row = 16 * w + (l & 15);
        const int q = l >> 4;
        float x[8];
        *(float4*)&x[0] = *(float4*)&sEV[row * 36 + 8 * q];
        *(float4*)&x[4] = *(float4*)&sEV[row * 36 + 8 * q + 4];
        float s = x[0] + x[1] + x[2] + x[3] + x[4] + x[5] + x[6] + x[7];
        s += __shfl_xor(s, 16, 64); s += __shfl_xor(s, 32, 64);
        float mu = s * (1.f / 32.f);
        float v2 = 0.f;
        #pragma unroll
        for (int i = 0; i < 8; i++) { float d = x[i] - mu; v2 += d * d; }
        v2 += __shfl_xor(v2, 16, 64); v2 += __shfl_xor(v2, 32, 64);
        float rs = rsqrtf(v2 * (1.f / 32.f) + 1e-5f);
        float4 g1 = *(const float4*)(ge1 + 8 * q), g2 = *(const float4*)(ge1 + 8 * q + 4);
        float4 b1 = *(const float4*)(be1 + 8 * q), b2 = *(const float4*)(be1 + 8 * q + 4);
        float4 y0, y1;
        y0.x = (x[0] - mu) * rs * g1.x + b1.x;
        y0.y = (x[1] - mu) * rs * g1.y + b1.y;
        y0.z = (x[2] - mu) * rs * g1.z + b1.z;
        y0.w = (x[3] - mu) * rs * g1.w + b1.w;
        y1.x = (x[4] - mu) * rs * g2.x + b2.x;
        y1.y = (x[5] - mu) * rs * g2.y + b2.y;
        y1.z = (x[6] - mu) * rs * g2.z + b2.z;
        y1.w = (x[7] - mu) * rs * g2.w + b2.w;
        *(float4*)&sN[row * 36 + 8 * q]     = y0;
        *(float4*)&sN[row * 36 + 8 * q + 4] = y1;
    }
    __syncthreads();

    // ---- S6: GEMM2  F[64][64] = relu(en @ Wf0 + bf0) -> sF rows ----
    {
        float acc2[4][4] = {};
        #pragma unroll
        for (int kc = 0; kc < 32; kc += 4) {
            float4 b0 = *(float4*)&sW[(kc + 0) * 68 + tx * 4];
            float4 b1 = *(float4*)&sW[(kc + 1) * 68 + tx * 4];
            float4 b2 = *(float4*)&sW[(kc + 2) * 68 + tx * 4];
            float4 b3 = *(float4*)&sW[(kc + 3) * 68 + tx * 4];
            #pragma unroll
            for (int i = 0; i < 4; i++) {
                float4 a = *(float4*)&sN[(ty * 4 + i) * 36 + kc];
                acc2[i][0] += a.x * b0.x + a.y * b1.x + a.z * b2.x + a.w * b3.x;
                acc2[i][1] += a.x * b0.y + a.y * b1.y + a.z * b2.y + a.w * b3.y;
                acc2[i][2] += a.x * b0.z + a.y * b1.z + a.z * b2.z + a.w * b3.z;
                acc2[i][3] += a.x * b0.w + a.y * b1.w + a.z * b2.w + a.w * b3.w;
            }
        }
        float4 bf0v = *(const float4*)(bf0 + tx * 4);
        #pragma unroll
        for (int i = 0; i < 4; i++) {
            float4 f;
            f.x = fmaxf(acc2[i][0] + bf0v.x, 0.f);
            f.y = fmaxf(acc2[i][1] + bf0v.y, 0.f);
            f.z = fmaxf(acc2[i][2] + bf0v.z, 0.f);
            f.w = fmaxf(acc2[i][3] + bf0v.w, 0.f);
            *(float4*)&sF[(ty * 4 + i) * 68 + tx * 4] = f;
        }
    }
    __syncthreads();

    // ---- S7: GEMM3  out[64][32] = F @ Wf1 + er + bf1 ----
    {
        float a20[4] = {0.f, 0.f, 0.f, 0.f};
        float a21[4] = {0.f, 0.f, 0.f, 0.f};
        #pragma unroll
        for (int kc = 0; kc < 64; kc += 4) {
            float2 w0 = *(float2*)&sW1[(kc + 0) * 36 + tx * 2];
            float2 w1 = *(float2*)&sW1[(kc + 1) * 36 + tx * 2];
            float2 w2 = *(float2*)&sW1[(kc + 2) * 36 + tx * 2];
            float2 w3 = *(float2*)&sW1[(kc + 3) * 36 + tx * 2];
            #pragma unroll
            for (int i = 0; i < 4; i++) {
                float4 f = *(float4*)&sF[(ty * 4 + i) * 68 + kc];
                a20[i] += f.x * w0.x + f.y * w1.x + f.z * w2.x + f.w * w3.x;
                a21[i] += f.x * w0.y + f.y * w1.y + f.z * w2.y + f.w * w3.y;
            }
        }
        int c = tx * 2;
        float f1a = bf1[c], f1b = bf1[c + 1];
        #pragma unroll
        for (int i = 0; i < 4; i++) {
            int rowi = ty * 4 + i;
            long long e = e0 + rowi;
            if (e < E) {
                float2 st;
                st.x = a20[i] + sEV[rowi * 36 + c]     + f1a;
                st.y = a21[i] + sEV[rowi * 36 + c + 1] + f1b;
                *(float2*)(eout + e * 32 + c) = st;
            }
        }
    }
}

// ---------------- gather: one wave per node, halves process alt. edges -----
__global__ __launch_bounds__(256) void gather_kernel(
    const float* __restrict__ exve, const float* __restrict__ qkv,
    const int* __restrict__ src, const int* __restrict__ eidx,
    const int* __restrict__ off, const int* __restrict__ cnt,
    float* __restrict__ agg, int N)
{
    __shared__ float sV[4][2][96];
    __shared__ float sE[4][2][64];
    const int wave = threadIdx.x >> 6;
    const int lane = threadIdx.x & 63;
    const int head = lane & 31;
    const int half = lane >> 5;
    int n = blockIdx.x * 4 + wave;
    if (n >= N) return;
    const int o = off[n], d = cnt[n];
    float a0 = 0.f, a1 = 0.f, a2 = 0.f, a3 = 0.f, den = 0.f;
    for (int i = half; i < d; i += 2) {
        int e = eidx[o + i];
        int sn = src[e];
        const float* vr = qkv + (size_t)sn * 288 + 192;
        const float* er = exve + (size_t)e * 64;
        if (head < 24) {
            *(float4*)&sV[wave][half][head * 4] = *(const float4*)(vr + head * 4);
        } else {
            int j = head - 24;
            *(float4*)&sE[wave][half][j * 8]     = *(const float4*)(er + j * 8);
            *(float4*)&sE[wave][half][j * 8 + 4] = *(const float4*)(er + j * 8 + 4);
        }
        __builtin_amdgcn_wave_barrier();
        float ex = sE[wave][half][head];
        float vv = sE[wave][half][32 + head];
        a0 += ex * sV[wave][half][head * 3];
        a1 += ex * sV[wave][half][head * 3 + 1];
        a2 += ex * sV[wave][half][head * 3 + 2];
        a3 += ex * vv;
        den += ex;
        __builtin_amdgcn_wave_barrier();
    }
    a0 += __shfl_xor(a0, 32, 64);
    a1 += __shfl_xor(a1, 32, 64);
    a2 += __shfl_xor(a2, 32, 64);
    a3 += __shfl_xor(a3, 32, 64);
    den += __shfl_xor(den, 32, 64);
    if (half == 0) {
        float sc = (d > 0) ? 1.f / den : 0.f;
        float* ap = agg + (size_t)n * 128 + head * 4;
        ap[0] = a0 * sc; ap[1] = a1 * sc; ap[2] = a2 * sc; ap[3] = a3 * sc;
    }
}

// ---------------------------------------------------------------------------
extern "C" void kernel_launch(void* const* d_in, const int* in_sizes, int n_in,
                              void* d_out, int out_size, void* d_ws, size_t ws_size,
                              hipStream_t stream)
{
    (void)n_in; (void)out_size; (void)ws_size;
    const float* feat = (const float*)d_in[0];
    const float* edge = (const float*)d_in[1];
    const float* Wq   = (const float*)d_in[2];
    const float* bq   = (const float*)d_in[3];
    const float* Wk   = (const float*)d_in[4];
    const float* bk   = (const float*)d_in[5];
    const float* Wv   = (const float*)d_in[6];
    const float* bv   = (const float*)d_in[7];
    const float* We   = (const float*)d_in[8];
    const float* be   = (const float*)d_in[9];
    const float* Wb   = (const float*)d_in[10];
    const float* bb   = (const float*)d_in[11];
    const float* Wvv  = (const float*)d_in[12];
    const float* bvv  = (const float*)d_in[13];
    const float* Wf0  = (const float*)d_in[14];
    const float* bf0  = (const float*)d_in[15];
    const float* Wf1  = (const float*)d_in[16];
    const float* bf1  = (const float*)d_in[17];
    const float* Wm0  = (const float*)d_in[18];
    const float* bm0  = (const float*)d_in[19];
    const float* Wm1  = (const float*)d_in[20];
    const float* bm1  = (const float*)d_in[21];
    const float* g_n0 = (const float*)d_in[22];
    const float* b_n0 = (const float*)d_in[23];
    const float* g_e0 = (const float*)d_in[24];
    const float* b_e0 = (const float*)d_in[25];
    const float* g_e1 = (const float*)d_in[26];
    const float* b_e1 = (const float*)d_in[27];
    const float* g_m  = (const float*)d_in[28];
    const float* b_m  = (const float*)d_in[29];
    const float* wsc  = (const float*)d_in[30];
    const int*   src  = (const int*)d_in[31];
    const int*   dst  = (const int*)d_in[32];

    const int N = in_sizes[0] / 96;
    const int E = in_sizes[1] / 32;

    float* ws    = (float*)d_ws;
    float* qkv   = ws;                                  // N*288
    float* agg   = qkv + (size_t)N * 288;               // N*128
    float* h0    = agg + (size_t)N * 128;               // N*96 (h0, later hn)
    float* hp    = h0 + (size_t)N * 96;                 // N*96
    float* exve  = hp + (size_t)N * 96;                 // E*64 = {ex|ve}
    int*   eidx  = (int*)(exve + (size_t)E * 64);       // E
    int*   cnt   = eidx + E;                            // N
    int*   offv  = cnt + N;                             // N
    int*   cur   = offv + N;                            // N
    float* tbuf  = ws;                                  // N*192, reuses qkv late
    float* hout  = (float*)d_out;
    float* eoutp = (float*)d_out + (size_t)N * 96;      // also hosts qk scores

    hipMemsetAsync(cnt, 0, (size_t)N * sizeof(int), stream);

    const int mt = (N + 63) / 64;
    const int et = (E + 255) / 256;

    // CSR bucketing (independent of node-side work)
    count_kernel<<<et, 256, 0, stream>>>(dst, cnt, E);
    scan_kernel<<<1, 1024, 0, stream>>>(cnt, offv, cur, N);
    scatter_kernel<<<et, 256, 0, stream>>>(dst, cur, eidx, E);

    // node side: h0 = LN(feat); qkv = h0 @ [Wq|Wk|Wv]
    ln96_kernel<<<(N + 7) / 8, 256, 0, stream>>>(feat, g_n0, b_n0, h0, N);
    gemm_kernel<0,0><<<dim3(mt, 2), 192, 0, stream>>>(h0, 96, Wq, 96, bq, nullptr, nullptr, qkv, 288, 0,   N, 96);
    gemm_kernel<0,0><<<dim3(mt, 2), 192, 0, stream>>>(h0, 96, Wk, 96, bk, nullptr, nullptr, qkv, 288, 96,  N, 96);
    gemm_kernel<0,0><<<dim3(mt, 2), 192, 0, stream>>>(h0, 96, Wv, 96, bv, nullptr, nullptr, qkv, 288, 192, N, 96);

    // scores -> eoutp region (qk buffer); edge tile pass consumes + overwrites
    score_kernel<<<(E + 7) / 8, 256, 0, stream>>>(qkv, src, dst, eoutp, E);
    edge_tile_kernel<<<(E + 63) / 64, 256, 0, stream>>>(edge, eoutp,
                                             We, be, Wb, bb, Wf0, bf0, Wf1, bf1,
                                             g_e0, b_e0, g_e1, b_e1,
                                             exve, eoutp, E);

    // gather per node -> normalized agg[N,128]
    gather_kernel<<<(N + 3) / 4, 256, 0, stream>>>(exve, qkv, src, eidx, offv, cnt, agg, N);

    // h_pre = feat*(1+w) + agg @ Wvv + bvv
    gemm_kernel<0,1><<<dim3(mt, 2), 192, 0, stream>>>(agg, 128, Wvv, 96, bvv, feat, wsc, hp, 96, 0, N, 128);
    // hn = LN(h_pre)
    ln96_kernel<<<(N + 7) / 8, 256, 0, stream>>>(hp, g_m, b_m, h0, N);
    // t = relu(hn @ Wm0 + bm0)
    gemm_kernel<1,0><<<dim3(mt, 4), 192, 0, stream>>>(h0, 96, Wm0, 192, bm0, nullptr, nullptr, tbuf, 192, 0, N, 96);
    // h_out = h_pre + t @ Wm1 + bm1
    gemm_kernel<0,1><<<dim3(mt, 2), 192, 0, stream>>>(tbuf, 192, Wm1, 96, bm1, hp, nullptr, hout, 96, 0, N, 192);
}

// Round 10
// 1221.986 us; speedup vs baseline: 1.7020x; 1.5676x over previous
//
#include <hip/hip_runtime.h>
#include <cstdint>
#include <cstddef>

// ---------------------------------------------------------------------------
// EGT layer.  N nodes (DIM=96, H=32, HD=3), E edges.
// edge_tile_kernel: 64-edge tile per 256-thread block; the three [64x64x32]
// matvec GEMMs run on MFMA (bf16 in, f32 accum).  exve streamed as bf16.
// Atomic-free aggregation via CSR bucketing.
// ---------------------------------------------------------------------------

typedef short  s16x8 __attribute__((ext_vector_type(8)));
typedef short  s16x4 __attribute__((ext_vector_type(4)));
typedef float  f32x4 __attribute__((ext_vector_type(4)));

__device__ __forceinline__ unsigned short f2b(float x) {
    union { float f; unsigned u; } v; v.f = x;
    unsigned r = v.u + 0x7FFF + ((v.u >> 16) & 1);   // RNE
    return (unsigned short)(r >> 16);
}
__device__ __forceinline__ float b2f(unsigned short u) {
    union { unsigned u; float f; } v; v.u = ((unsigned)u) << 16; return v.f;
}

__device__ __forceinline__ float red32(float v) {
    #pragma unroll
    for (int m = 16; m >= 1; m >>= 1) v += __shfl_xor(v, m, 64);
    return v;
}

// ---------------- row LayerNorm over D=96 ----------------
__global__ __launch_bounds__(256) void ln96_kernel(
    const float* __restrict__ x, const float* __restrict__ g,
    const float* __restrict__ b, float* __restrict__ y, int M)
{
    int lane = threadIdx.x & 31;
    int grp  = threadIdx.x >> 5;
    int r = blockIdx.x * 8 + grp;
    if (r >= M) return;
    const float* xr = x + (size_t)r * 96;
    float a0 = xr[lane], a1 = xr[lane + 32], a2 = xr[lane + 64];
    float mu = red32(a0 + a1 + a2) * (1.f / 96.f);
    float d0 = a0 - mu, d1 = a1 - mu, d2 = a2 - mu;
    float var = red32(d0 * d0 + d1 * d1 + d2 * d2) * (1.f / 96.f);
    float rs = rsqrtf(var + 1e-5f);
    float* yr = y + (size_t)r * 96;
    yr[lane]      = d0 * rs * g[lane]      + b[lane];
    yr[lane + 32] = d1 * rs * g[lane + 32] + b[lane + 32];
    yr[lane + 64] = d2 * rs * g[lane + 64] + b[lane + 64];
}

// ---------------- generic small-N GEMM: C[M,*] = A[M,K] @ B[K,*] + bias -----
template<int RELU, int RES>
__global__ __launch_bounds__(192) void gemm_kernel(
    const float* __restrict__ A, int lda,
    const float* __restrict__ B, int ldb,
    const float* __restrict__ bias,
    const float* __restrict__ resid,
    const float* __restrict__ wptr,
    float* __restrict__ C, int ldc, int n0,
    int M, int K)
{
    __shared__ float sA[32 * 68];
    __shared__ float sB[32 * 48];
    const int tid = threadIdx.x;
    const int tx = tid % 12;
    const int ty = tid / 12;
    const int m0 = blockIdx.x * 64;
    const int nb = blockIdx.y * 48;
    float acc[4][4] = {};

    for (int kc = 0; kc < K; kc += 32) {
        for (int idx = tid; idx < 64 * 32; idx += 192) {
            int m = idx >> 5, k = idx & 31;
            int row = m0 + m;
            sA[k * 68 + m] = (row < M) ? A[(size_t)row * lda + kc + k] : 0.f;
        }
        for (int idx = tid; idx < 32 * 48; idx += 192) {
            int k = idx / 48, n = idx - k * 48;
            sB[idx] = B[(size_t)(kc + k) * ldb + nb + n];
        }
        __syncthreads();
        #pragma unroll
        for (int k = 0; k < 32; k++) {
            float4 av = *(const float4*)&sA[k * 68 + ty * 4];
            float4 bv = *(const float4*)&sB[k * 48 + tx * 4];
            float a4[4] = {av.x, av.y, av.z, av.w};
            float b4[4] = {bv.x, bv.y, bv.z, bv.w};
            #pragma unroll
            for (int i = 0; i < 4; i++)
                #pragma unroll
                for (int j = 0; j < 4; j++)
                    acc[i][j] += a4[i] * b4[j];
        }
        __syncthreads();
    }

    float scale = 1.f;
    if (RES) scale = wptr ? (1.f + wptr[0]) : 1.f;
    #pragma unroll
    for (int i = 0; i < 4; i++) {
        int row = m0 + ty * 4 + i;
        if (row >= M) continue;
        #pragma unroll
        for (int j = 0; j < 4; j++) {
            int col = nb + tx * 4 + j;
            float v = acc[i][j] + bias[col];
            if (RELU) v = fmaxf(v, 0.f);
            if (RES) v += scale * resid[(size_t)row * ldc + n0 + col];
            C[(size_t)row * ldc + n0 + col] = v;
        }
    }
}

// ---------------- CSR bucketing ----------------
__global__ __launch_bounds__(256) void count_kernel(
    const int* __restrict__ dst, int* __restrict__ cnt, int E)
{
    int i = blockIdx.x * 256 + threadIdx.x;
    if (i < E) atomicAdd(&cnt[dst[i]], 1);
}

__global__ __launch_bounds__(1024) void scan_kernel(
    const int* __restrict__ cnt, int* __restrict__ off, int* __restrict__ cur, int N)
{
    __shared__ int s[1024];
    const int tid = threadIdx.x;
    const int chunk = (N + 1023) >> 10;
    const int lo = tid * chunk;
    const int hi = min(lo + chunk, N);
    int sum = 0;
    for (int i = lo; i < hi; i++) sum += cnt[i];
    s[tid] = sum;
    __syncthreads();
    for (int d = 1; d < 1024; d <<= 1) {
        int v = (tid >= d) ? s[tid - d] : 0;
        __syncthreads();
        s[tid] += v;
        __syncthreads();
    }
    int base = (tid == 0) ? 0 : s[tid - 1];
    for (int i = lo; i < hi; i++) {
        off[i] = base; cur[i] = base;
        base += cnt[i];
    }
}

__global__ __launch_bounds__(256) void scatter_kernel(
    const int* __restrict__ dst, int* __restrict__ cur,
    int* __restrict__ eidx, int E)
{
    int i = blockIdx.x * 256 + threadIdx.x;
    if (i < E) {
        int p = atomicAdd(&cur[dst[i]], 1);
        eidx[p] = i;
    }
}

// ---------------- score: qk[e][h] = 0.5 * <k[src][h], q[dst][h]> -----------
__global__ __launch_bounds__(256) void score_kernel(
    const float* __restrict__ qkv, const int* __restrict__ src,
    const int* __restrict__ dst, float* __restrict__ qk, int E)
{
    __shared__ float sQ[8][96], sK[8][96];
    const int lane = threadIdx.x & 31;
    const int grp  = threadIdx.x >> 5;
    long long e = (long long)blockIdx.x * 8 + grp;
    if (e >= E) return;
    int sn = src[e], dn = dst[e];
    if (lane < 24) {
        float4 qv = *(const float4*)(qkv + (size_t)dn * 288 + lane * 4);
        float4 kv = *(const float4*)(qkv + (size_t)sn * 288 + 96 + lane * 4);
        *(float4*)&sQ[grp][lane * 4] = qv;
        *(float4*)&sK[grp][lane * 4] = kv;
    }
    __builtin_amdgcn_wave_barrier();
    float q0 = sQ[grp][lane * 3], q1 = sQ[grp][lane * 3 + 1], q2 = sQ[grp][lane * 3 + 2];
    float k0 = sK[grp][lane * 3], k1 = sK[grp][lane * 3 + 1], k2 = sK[grp][lane * 3 + 2];
    qk[e * 32 + lane] = (k0 * q0 + k1 * q1 + k2 * q2) * 0.5f;
}

// ---------------- edge tile kernel: 64 edges per block, MFMA GEMMs ----------
// exve (bf16) layout: [E][64] = {ex[0..32), ve[32..64)}
__global__ __launch_bounds__(256, 4) void edge_tile_kernel(
    const float* __restrict__ edge, const float* __restrict__ qk,
    const float* __restrict__ We, const float* __restrict__ be,
    const float* __restrict__ Wb, const float* __restrict__ bb,
    const float* __restrict__ Wf0, const float* __restrict__ bf0,
    const float* __restrict__ Wf1, const float* __restrict__ bf1,
    const float* __restrict__ ge0, const float* __restrict__ be0,
    const float* __restrict__ ge1, const float* __restrict__ be1,
    unsigned short* __restrict__ exve16, float* __restrict__ eout, int E)
{
    __shared__ float          sEV[64 * 36];   // ev rows -> er rows -> out rows
    __shared__ unsigned short sQK[64 * 36];   // qk tile, bf16
    __shared__ unsigned short sA [64 * 40];   // LN outputs (ew, later en), bf16 [M][K]
    __shared__ unsigned short sB [64 * 40];   // Wb|We then Wf0, bf16 [N][K]
    __shared__ unsigned short sB2[32 * 72];   // Wf1^T, bf16 [N=32][K=64]
    __shared__ unsigned short sX [64 * 72];   // ex|ve staging, then F rows [M][K=64]
    // total 37,888 B -> 4 blocks/CU

    const int tid = threadIdx.x;
    const long long e0 = (long long)blockIdx.x * 64;
    const int w  = tid >> 6;        // wave id: owns output rows 16w..16w+15
    const int l  = tid & 63;
    const int fr = l & 15;          // fragment row/col index
    const int kg = l >> 4;          // k-group

    // ---- S1: stage ev (f32), qk (bf16), Wb|We^T (bf16), Wf1^T (bf16) ----
    #pragma unroll
    for (int rr = 0; rr < 2; rr++) {
        int idx = tid + 256 * rr;
        int row = idx >> 3, c4 = (idx & 7) * 4;
        long long e = e0 + row;
        float4 v = make_float4(0.f, 0.f, 0.f, 0.f);
        if (e < E) v = *(const float4*)(edge + e * 32 + c4);
        *(float4*)&sEV[row * 36 + c4] = v;
        float4 q = make_float4(0.f, 0.f, 0.f, 0.f);
        if (e < E) q = *(const float4*)(qk + e * 32 + c4);
        s16x4 qb; qb[0] = (short)f2b(q.x); qb[1] = (short)f2b(q.y);
        qb[2] = (short)f2b(q.z); qb[3] = (short)f2b(q.w);
        *(s16x4*)&sQK[row * 36 + c4] = qb;
    }
    {
        int k = tid >> 3, c4 = (tid & 7) * 4;          // k 0..31, c4 0..28
        float4 vb = *(const float4*)(Wb + k * 32 + c4);
        float4 ve = *(const float4*)(We + k * 32 + c4);
        sB[(c4 + 0) * 40 + k] = f2b(vb.x); sB[(c4 + 1) * 40 + k] = f2b(vb.y);
        sB[(c4 + 2) * 40 + k] = f2b(vb.z); sB[(c4 + 3) * 40 + k] = f2b(vb.w);
        sB[(32 + c4 + 0) * 40 + k] = f2b(ve.x); sB[(32 + c4 + 1) * 40 + k] = f2b(ve.y);
        sB[(32 + c4 + 2) * 40 + k] = f2b(ve.z); sB[(32 + c4 + 3) * 40 + k] = f2b(ve.w);
    }
    #pragma unroll
    for (int rr = 0; rr < 2; rr++) {
        int idx = tid + 256 * rr;
        int k = idx >> 3, c4 = (idx & 7) * 4;          // k 0..63, c4 0..28
        float4 v = *(const float4*)(Wf1 + k * 32 + c4);
        sB2[(c4 + 0) * 72 + k] = f2b(v.x); sB2[(c4 + 1) * 72 + k] = f2b(v.y);
        sB2[(c4 + 2) * 72 + k] = f2b(v.z); sB2[(c4 + 3) * 72 + k] = f2b(v.w);
    }
    __syncthreads();

    // ---- S2: LN1 -> ew rows (bf16) in sA ----
    {
        const int row = 16 * w + (tid & 15);
        const int q = (tid & 63) >> 4;
        float x[8];
        *(float4*)&x[0] = *(float4*)&sEV[row * 36 + 8 * q];
        *(float4*)&x[4] = *(float4*)&sEV[row * 36 + 8 * q + 4];
        float s = x[0] + x[1] + x[2] + x[3] + x[4] + x[5] + x[6] + x[7];
        s += __shfl_xor(s, 16, 64); s += __shfl_xor(s, 32, 64);
        float mu = s * (1.f / 32.f);
        float v2 = 0.f;
        #pragma unroll
        for (int i = 0; i < 8; i++) { float d = x[i] - mu; v2 += d * d; }
        v2 += __shfl_xor(v2, 16, 64); v2 += __shfl_xor(v2, 32, 64);
        float rs = rsqrtf(v2 * (1.f / 32.f) + 1e-5f);
        float4 g1 = *(const float4*)(ge0 + 8 * q), g2 = *(const float4*)(ge0 + 8 * q + 4);
        float4 b1 = *(const float4*)(be0 + 8 * q), b2 = *(const float4*)(be0 + 8 * q + 4);
        float gg[8] = {g1.x, g1.y, g1.z, g1.w, g2.x, g2.y, g2.z, g2.w};
        float bs[8] = {b1.x, b1.y, b1.z, b1.w, b2.x, b2.y, b2.z, b2.w};
        s16x8 y;
        #pragma unroll
        for (int i = 0; i < 8; i++)
            y[i] = (short)f2b((x[i] - mu) * rs * gg[i] + bs[i]);
        *(s16x8*)&sA[row * 40 + 8 * q] = y;
    }
    __syncthreads();

    // ---- S3: GEMM1 (MFMA)  [64][64 = sc|veh] = ew @ [Wb|We] ----
    f32x4 acc[4];
    {
        s16x8 a = *(s16x8*)&sA[(16 * w + fr) * 40 + kg * 8];
        #pragma unroll
        for (int nt = 0; nt < 4; nt++) {
            s16x8 b = *(s16x8*)&sB[(16 * nt + fr) * 40 + kg * 8];
            f32x4 z = {0.f, 0.f, 0.f, 0.f};
            acc[nt] = __builtin_amdgcn_mfma_f32_16x16x32_bf16(a, b, z, 0, 0, 0);
        }
    }
    __syncthreads();

    // ---- S4: epilogue1 (exp -> sX; er -> sEV) + restage Wf0 -> sB ----
    #pragma unroll
    for (int nt = 0; nt < 2; nt++) {
        int col = nt * 16 + fr;
        float bbv = bb[col];
        #pragma unroll
        for (int r = 0; r < 4; r++) {
            int row = 16 * w + 4 * kg + r;
            float sc = acc[nt][r] + b2f(sQK[row * 36 + col]) + bbv;
            sX[row * 72 + col] = f2b(__expf(sc));
            float er = sc + sEV[row * 36 + col];
            sEV[row * 36 + col] = er;
        }
    }
    #pragma unroll
    for (int nt = 2; nt < 4; nt++) {
        int col = (nt - 2) * 16 + fr;
        float bev = be[col];
        #pragma unroll
        for (int r = 0; r < 4; r++) {
            int row = 16 * w + 4 * kg + r;
            sX[row * 72 + 32 + col] = f2b(acc[nt][r] + bev);
        }
    }
    #pragma unroll
    for (int rr = 0; rr < 2; rr++) {
        int idx = tid + 256 * rr;
        int k = idx >> 4, c4 = (idx & 15) * 4;         // k 0..31, c4 0..60
        float4 v = *(const float4*)(Wf0 + k * 64 + c4);
        sB[(c4 + 0) * 40 + k] = f2b(v.x); sB[(c4 + 1) * 40 + k] = f2b(v.y);
        sB[(c4 + 2) * 40 + k] = f2b(v.z); sB[(c4 + 3) * 40 + k] = f2b(v.w);
    }
    __syncthreads();

    // ---- S5: copy sX -> exve16 ; LN2 (er -> en bf16 in sA) ----
    #pragma unroll
    for (int rr = 0; rr < 2; rr++) {
        int idx = tid + 256 * rr;
        int row = idx >> 3, c8 = (idx & 7) * 8;
        long long e = e0 + row;
        if (e < E)
            *(s16x8*)(exve16 + e * 64 + c8) = *(s16x8*)&sX[row * 72 + c8];
    }
    {
        const int row = 16 * w + (tid & 15);
        const int q = (tid & 63) >> 4;
        float x[8];
        *(float4*)&x[0] = *(float4*)&sEV[row * 36 + 8 * q];
        *(float4*)&x[4] = *(float4*)&sEV[row * 36 + 8 * q + 4];
        float s = x[0] + x[1] + x[2] + x[3] + x[4] + x[5] + x[6] + x[7];
        s += __shfl_xor(s, 16, 64); s += __shfl_xor(s, 32, 64);
        float mu = s * (1.f / 32.f);
        float v2 = 0.f;
        #pragma unroll
        for (int i = 0; i < 8; i++) { float d = x[i] - mu; v2 += d * d; }
        v2 += __shfl_xor(v2, 16, 64); v2 += __shfl_xor(v2, 32, 64);
        float rs = rsqrtf(v2 * (1.f / 32.f) + 1e-5f);
        float4 g1 = *(const float4*)(ge1 + 8 * q), g2 = *(const float4*)(ge1 + 8 * q + 4);
        float4 b1 = *(const float4*)(be1 + 8 * q), b2 = *(const float4*)(be1 + 8 * q + 4);
        float gg[8] = {g1.x, g1.y, g1.z, g1.w, g2.x, g2.y, g2.z, g2.w};
        float bs[8] = {b1.x, b1.y, b1.z, b1.w, b2.x, b2.y, b2.z, b2.w};
        s16x8 y;
        #pragma unroll
        for (int i = 0; i < 8; i++)
            y[i] = (short)f2b((x[i] - mu) * rs * gg[i] + bs[i]);
        *(s16x8*)&sA[row * 40 + 8 * q] = y;
    }
    __syncthreads();

    // ---- S6: GEMM2 (MFMA)  F[64][64] = relu(en @ Wf0 + bf0) -> sX rows ----
    {
        s16x8 a = *(s16x8*)&sA[(16 * w + fr) * 40 + kg * 8];
        #pragma unroll
        for (int nt = 0; nt < 4; nt++) {
            s16x8 b = *(s16x8*)&sB[(16 * nt + fr) * 40 + kg * 8];
            f32x4 z = {0.f, 0.f, 0.f, 0.f};
            f32x4 a2 = __builtin_amdgcn_mfma_f32_16x16x32_bf16(a, b, z, 0, 0, 0);
            int col = nt * 16 + fr;
            float b0v = bf0[col];
            #pragma unroll
            for (int r = 0; r < 4; r++) {
                int row = 16 * w + 4 * kg + r;
                sX[row * 72 + col] = f2b(fmaxf(a2[r] + b0v, 0.f));
            }
        }
    }
    __syncthreads();

    // ---- S7: GEMM3 (MFMA)  out[64][32] = F @ Wf1 + er + bf1 -> sEV ----
    {
        s16x8 a0 = *(s16x8*)&sX[(16 * w + fr) * 72 + kg * 8];
        s16x8 a1 = *(s16x8*)&sX[(16 * w + fr) * 72 + 32 + kg * 8];
        #pragma unroll
        for (int nt = 0; nt < 2; nt++) {
            s16x8 b0 = *(s16x8*)&sB2[(16 * nt + fr) * 72 + kg * 8];
            s16x8 b1 = *(s16x8*)&sB2[(16 * nt + fr) * 72 + 32 + kg * 8];
            f32x4 z = {0.f, 0.f, 0.f, 0.f};
            f32x4 t = __builtin_amdgcn_mfma_f32_16x16x32_bf16(a0, b0, z, 0, 0, 0);
            t = __builtin_amdgcn_mfma_f32_16x16x32_bf16(a1, b1, t, 0, 0, 0);
            int col = nt * 16 + fr;
            float bf1v = bf1[col];
            #pragma unroll
            for (int r = 0; r < 4; r++) {
                int row = 16 * w + 4 * kg + r;
                float out = t[r] + sEV[row * 36 + col] + bf1v;
                sEV[row * 36 + col] = out;
            }
        }
    }
    __syncthreads();

    // ---- S8: copy sEV[:, 0..32) -> eout ----
    #pragma unroll
    for (int rr = 0; rr < 2; rr++) {
        int idx = tid + 256 * rr;
        int row = idx >> 3, c4 = (idx & 7) * 4;
        long long e = e0 + row;
        if (e < E)
            *(float4*)(eout + e * 32 + c4) = *(float4*)&sEV[row * 36 + c4];
    }
}

// ---------------- gather: one wave per node, halves process alt. edges -----
__global__ __launch_bounds__(256) void gather_kernel(
    const unsigned short* __restrict__ exve16, const float* __restrict__ qkv,
    const int* __restrict__ src, const int* __restrict__ eidx,
    const int* __restrict__ off, const int* __restrict__ cnt,
    float* __restrict__ agg, int N)
{
    __shared__ float sV[4][2][96];
    __shared__ unsigned short sE16[4][2][64];
    const int wave = threadIdx.x >> 6;
    const int lane = threadIdx.x & 63;
    const int head = lane & 31;
    const int half = lane >> 5;
    int n = blockIdx.x * 4 + wave;
    if (n >= N) return;
    const int o = off[n], d = cnt[n];
    float a0 = 0.f, a1 = 0.f, a2 = 0.f, a3 = 0.f, den = 0.f;
    for (int i = half; i < d; i += 2) {
        int e = eidx[o + i];
        int sn = src[e];
        const float* vr = qkv + (size_t)sn * 288 + 192;
        const unsigned short* er = exve16 + (size_t)e * 64;
        if (head < 24) {
            *(float4*)&sV[wave][half][head * 4] = *(const float4*)(vr + head * 4);
        } else {
            int j = head - 24;
            *(s16x8*)&sE16[wave][half][j * 8] = *(const s16x8*)(er + j * 8);
        }
        __builtin_amdgcn_wave_barrier();
        float ex = b2f(sE16[wave][half][head]);
        float vv = b2f(sE16[wave][half][32 + head]);
        a0 += ex * sV[wave][half][head * 3];
        a1 += ex * sV[wave][half][head * 3 + 1];
        a2 += ex * sV[wave][half][head * 3 + 2];
        a3 += ex * vv;
        den += ex;
        __builtin_amdgcn_wave_barrier();
    }
    a0 += __shfl_xor(a0, 32, 64);
    a1 += __shfl_xor(a1, 32, 64);
    a2 += __shfl_xor(a2, 32, 64);
    a3 += __shfl_xor(a3, 32, 64);
    den += __shfl_xor(den, 32, 64);
    if (half == 0) {
        float sc = (d > 0) ? 1.f / den : 0.f;
        float* ap = agg + (size_t)n * 128 + head * 4;
        ap[0] = a0 * sc; ap[1] = a1 * sc; ap[2] = a2 * sc; ap[3] = a3 * sc;
    }
}

// ---------------------------------------------------------------------------
extern "C" void kernel_launch(void* const* d_in, const int* in_sizes, int n_in,
                              void* d_out, int out_size, void* d_ws, size_t ws_size,
                              hipStream_t stream)
{
    (void)n_in; (void)out_size; (void)ws_size;
    const float* feat = (const float*)d_in[0];
    const float* edge = (const float*)d_in[1];
    const float* Wq   = (const float*)d_in[2];
    const float* bq   = (const float*)d_in[3];
    const float* Wk   = (const float*)d_in[4];
    const float* bk   = (const float*)d_in[5];
    const float* Wv   = (const float*)d_in[6];
    const float* bv   = (const float*)d_in[7];
    const float* We   = (const float*)d_in[8];
    const float* be   = (const float*)d_in[9];
    const float* Wb   = (const float*)d_in[10];
    const float* bb   = (const float*)d_in[11];
    const float* Wvv  = (const float*)d_in[12];
    const float* bvv  = (const float*)d_in[13];
    const float* Wf0  = (const float*)d_in[14];
    const float* bf0  = (const float*)d_in[15];
    const float* Wf1  = (const float*)d_in[16];
    const float* bf1  = (const float*)d_in[17];
    const float* Wm0  = (const float*)d_in[18];
    const float* bm0  = (const float*)d_in[19];
    const float* Wm1  = (const float*)d_in[20];
    const float* bm1  = (const float*)d_in[21];
    const float* g_n0 = (const float*)d_in[22];
    const float* b_n0 = (const float*)d_in[23];
    const float* g_e0 = (const float*)d_in[24];
    const float* b_e0 = (const float*)d_in[25];
    const float* g_e1 = (const float*)d_in[26];
    const float* b_e1 = (const float*)d_in[27];
    const float* g_m  = (const float*)d_in[28];
    const float* b_m  = (const float*)d_in[29];
    const float* wsc  = (const float*)d_in[30];
    const int*   src  = (const int*)d_in[31];
    const int*   dst  = (const int*)d_in[32];

    const int N = in_sizes[0] / 96;
    const int E = in_sizes[1] / 32;

    float* ws    = (float*)d_ws;
    float* qkv   = ws;                                      // N*288 f32
    float* agg   = qkv + (size_t)N * 288;                   // N*128 f32
    float* h0    = agg + (size_t)N * 128;                   // N*96 f32
    float* hp    = h0 + (size_t)N * 96;                     // N*96 f32
    unsigned short* exve16 = (unsigned short*)(hp + (size_t)N * 96); // E*64 bf16
    int*   eidx  = (int*)(exve16 + (size_t)E * 64);         // E
    int*   cnt   = eidx + E;                                // N
    int*   offv  = cnt + N;                                 // N
    int*   cur   = offv + N;                                // N
    float* tbuf  = ws;                                      // N*192, reuses qkv late
    float* hout  = (float*)d_out;
    float* eoutp = (float*)d_out + (size_t)N * 96;          // qk scores then e-out

    hipMemsetAsync(cnt, 0, (size_t)N * sizeof(int), stream);

    const int mt = (N + 63) / 64;
    const int et = (E + 255) / 256;

    // CSR bucketing (independent of node-side work)
    count_kernel<<<et, 256, 0, stream>>>(dst, cnt, E);
    scan_kernel<<<1, 1024, 0, stream>>>(cnt, offv, cur, N);
    scatter_kernel<<<et, 256, 0, stream>>>(dst, cur, eidx, E);

    // node side: h0 = LN(feat); qkv = h0 @ [Wq|Wk|Wv]
    ln96_kernel<<<(N + 7) / 8, 256, 0, stream>>>(feat, g_n0, b_n0, h0, N);
    gemm_kernel<0,0><<<dim3(mt, 2), 192, 0, stream>>>(h0, 96, Wq, 96, bq, nullptr, nullptr, qkv, 288, 0,   N, 96);
    gemm_kernel<0,0><<<dim3(mt, 2), 192, 0, stream>>>(h0, 96, Wk, 96, bk, nullptr, nullptr, qkv, 288, 96,  N, 96);
    gemm_kernel<0,0><<<dim3(mt, 2), 192, 0, stream>>>(h0, 96, Wv, 96, bv, nullptr, nullptr, qkv, 288, 192, N, 96);

    // scores -> eoutp region (qk buffer); edge tile pass consumes + overwrites
    score_kernel<<<(E + 7) / 8, 256, 0, stream>>>(qkv, src, dst, eoutp, E);
    edge_tile_kernel<<<(E + 63) / 64, 256, 0, stream>>>(edge, eoutp,
                                             We, be, Wb, bb, Wf0, bf0, Wf1, bf1,
                                             g_e0, b_e0, g_e1, b_e1,
                                             exve16, eoutp, E);

    // gather per node -> normalized agg[N,128]
    gather_kernel<<<(N + 3) / 4, 256, 0, stream>>>(exve16, qkv, src, eidx, offv, cnt, agg, N);

    // h_pre = feat*(1+w) + agg @ Wvv + bvv
    gemm_kernel<0,1><<<dim3(mt, 2), 192, 0, stream>>>(agg, 128, Wvv, 96, bvv, feat, wsc, hp, 96, 0, N, 128);
    // hn = LN(h_pre)
    ln96_kernel<<<(N + 7) / 8, 256, 0, stream>>>(hp, g_m, b_m, h0, N);
    // t = relu(hn @ Wm0 + bm0)
    gemm_kernel<1,0><<<dim3(mt, 4), 192, 0, stream>>>(h0, 96, Wm0, 192, bm0, nullptr, nullptr, tbuf, 192, 0, N, 96);
    // h_out = h_pre + t @ Wm1 + bm1
    gemm_kernel<0,1><<<dim3(mt, 2), 192, 0, stream>>>(tbuf, 192, Wm1, 96, bm1, hp, nullptr, hout, 96, 0, N, 192);
}

// Round 11
// 1059.012 us; speedup vs baseline: 1.9639x; 1.1539x over previous
//
#include <hip/hip_runtime.h>
#include <cstdint>
#include <cstddef>

// ---------------------------------------------------------------------------
// EGT layer.  N nodes (DIM=96, H=32, HD=3), E edges.
// edge_tile_kernel: 64-edge tile per block; qk scores computed IN-KERNEL
// (score kernel fused away); three [64x64x32] GEMMs on MFMA bf16.
// exve written at CSR position (pos[e]) so gather reads are contiguous.
// ---------------------------------------------------------------------------

typedef short  s16x8 __attribute__((ext_vector_type(8)));
typedef short  s16x4 __attribute__((ext_vector_type(4)));
typedef float  f32x4 __attribute__((ext_vector_type(4)));

__device__ __forceinline__ unsigned short f2b(float x) {
    union { float f; unsigned u; } v; v.f = x;
    unsigned r = v.u + 0x7FFF + ((v.u >> 16) & 1);   // RNE
    return (unsigned short)(r >> 16);
}
__device__ __forceinline__ float b2f(unsigned short u) {
    union { unsigned u; float f; } v; v.u = ((unsigned)u) << 16; return v.f;
}

__device__ __forceinline__ float red32(float v) {
    #pragma unroll
    for (int m = 16; m >= 1; m >>= 1) v += __shfl_xor(v, m, 64);
    return v;
}

// ---------------- row LayerNorm over D=96 ----------------
__global__ __launch_bounds__(256) void ln96_kernel(
    const float* __restrict__ x, const float* __restrict__ g,
    const float* __restrict__ b, float* __restrict__ y, int M)
{
    int lane = threadIdx.x & 31;
    int grp  = threadIdx.x >> 5;
    int r = blockIdx.x * 8 + grp;
    if (r >= M) return;
    const float* xr = x + (size_t)r * 96;
    float a0 = xr[lane], a1 = xr[lane + 32], a2 = xr[lane + 64];
    float mu = red32(a0 + a1 + a2) * (1.f / 96.f);
    float d0 = a0 - mu, d1 = a1 - mu, d2 = a2 - mu;
    float var = red32(d0 * d0 + d1 * d1 + d2 * d2) * (1.f / 96.f);
    float rs = rsqrtf(var + 1e-5f);
    float* yr = y + (size_t)r * 96;
    yr[lane]      = d0 * rs * g[lane]      + b[lane];
    yr[lane + 32] = d1 * rs * g[lane + 32] + b[lane + 32];
    yr[lane + 64] = d2 * rs * g[lane + 64] + b[lane + 64];
}

// ---------------- generic small-N GEMM: C[M,*] = A[M,K] @ B[K,*] + bias -----
template<int RELU, int RES>
__global__ __launch_bounds__(192) void gemm_kernel(
    const float* __restrict__ A, int lda,
    const float* __restrict__ B, int ldb,
    const float* __restrict__ bias,
    const float* __restrict__ resid,
    const float* __restrict__ wptr,
    float* __restrict__ C, int ldc, int n0,
    int M, int K)
{
    __shared__ float sA[32 * 68];
    __shared__ float sB[32 * 48];
    const int tid = threadIdx.x;
    const int tx = tid % 12;
    const int ty = tid / 12;
    const int m0 = blockIdx.x * 64;
    const int nb = blockIdx.y * 48;
    float acc[4][4] = {};

    for (int kc = 0; kc < K; kc += 32) {
        for (int idx = tid; idx < 64 * 32; idx += 192) {
            int m = idx >> 5, k = idx & 31;
            int row = m0 + m;
            sA[k * 68 + m] = (row < M) ? A[(size_t)row * lda + kc + k] : 0.f;
        }
        for (int idx = tid; idx < 32 * 48; idx += 192) {
            int k = idx / 48, n = idx - k * 48;
            sB[idx] = B[(size_t)(kc + k) * ldb + nb + n];
        }
        __syncthreads();
        #pragma unroll
        for (int k = 0; k < 32; k++) {
            float4 av = *(const float4*)&sA[k * 68 + ty * 4];
            float4 bv = *(const float4*)&sB[k * 48 + tx * 4];
            float a4[4] = {av.x, av.y, av.z, av.w};
            float b4[4] = {bv.x, bv.y, bv.z, bv.w};
            #pragma unroll
            for (int i = 0; i < 4; i++)
                #pragma unroll
                for (int j = 0; j < 4; j++)
                    acc[i][j] += a4[i] * b4[j];
        }
        __syncthreads();
    }

    float scale = 1.f;
    if (RES) scale = wptr ? (1.f + wptr[0]) : 1.f;
    #pragma unroll
    for (int i = 0; i < 4; i++) {
        int row = m0 + ty * 4 + i;
        if (row >= M) continue;
        #pragma unroll
        for (int j = 0; j < 4; j++) {
            int col = nb + tx * 4 + j;
            float v = acc[i][j] + bias[col];
            if (RELU) v = fmaxf(v, 0.f);
            if (RES) v += scale * resid[(size_t)row * ldc + n0 + col];
            C[(size_t)row * ldc + n0 + col] = v;
        }
    }
}

// ---------------- CSR bucketing ----------------
__global__ __launch_bounds__(256) void count_kernel(
    const int* __restrict__ dst, int* __restrict__ cnt, int E)
{
    int i = blockIdx.x * 256 + threadIdx.x;
    if (i < E) atomicAdd(&cnt[dst[i]], 1);
}

__global__ __launch_bounds__(1024) void scan_kernel(
    const int* __restrict__ cnt, int* __restrict__ off, int* __restrict__ cur, int N)
{
    __shared__ int s[1024];
    const int tid = threadIdx.x;
    const int chunk = (N + 1023) >> 10;
    const int lo = tid * chunk;
    const int hi = min(lo + chunk, N);
    int sum = 0;
    for (int i = lo; i < hi; i++) sum += cnt[i];
    s[tid] = sum;
    __syncthreads();
    for (int d = 1; d < 1024; d <<= 1) {
        int v = (tid >= d) ? s[tid - d] : 0;
        __syncthreads();
        s[tid] += v;
        __syncthreads();
    }
    int base = (tid == 0) ? 0 : s[tid - 1];
    for (int i = lo; i < hi; i++) {
        off[i] = base; cur[i] = base;
        base += cnt[i];
    }
}

// scatter: pos[e] = CSR slot of edge e; srcs[slot] = src node of that edge.
__global__ __launch_bounds__(256) void scatter_kernel(
    const int* __restrict__ dst, const int* __restrict__ src,
    int* __restrict__ cur, int* __restrict__ pos, int* __restrict__ srcs, int E)
{
    int i = blockIdx.x * 256 + threadIdx.x;
    if (i < E) {
        int p = atomicAdd(&cur[dst[i]], 1);
        pos[i] = p;
        srcs[p] = src[i];
    }
}

// ---------------- edge tile kernel: 64 edges per block, MFMA GEMMs ----------
// Computes qk in-kernel.  exve16 (bf16) written at CSR slot pos[e]:
// layout [slot][64] = {ex[0..32), ve[32..64)}.
__global__ __launch_bounds__(256, 4) void edge_tile_kernel(
    const float* __restrict__ edge, const float* __restrict__ qkv,
    const int* __restrict__ src, const int* __restrict__ dst,
    const int* __restrict__ pos,
    const float* __restrict__ We, const float* __restrict__ be,
    const float* __restrict__ Wb, const float* __restrict__ bb,
    const float* __restrict__ Wf0, const float* __restrict__ bf0,
    const float* __restrict__ Wf1, const float* __restrict__ bf1,
    const float* __restrict__ ge0, const float* __restrict__ be0,
    const float* __restrict__ ge1, const float* __restrict__ be1,
    unsigned short* __restrict__ exve16, float* __restrict__ eout, int E)
{
    __shared__ float          sEV[64 * 36];   // ev rows -> er rows -> out rows
    __shared__ unsigned short sQK[64 * 40];   // qk tile, bf16
    __shared__ unsigned short sA [64 * 40];   // LN outputs (ew/en), bf16 [M][K]
    __shared__ unsigned short sB [64 * 40];   // Wb|We then Wf0, bf16 [N][K]
    __shared__ unsigned short sB2[32 * 72];   // Wf1^T, bf16 [N=32][K=64]
    __shared__ unsigned short sX [64 * 72];   // ex|ve staging, then F rows
    // total 38,400 B -> 4 blocks/CU

    const int tid = threadIdx.x;
    const long long e0 = (long long)blockIdx.x * 64;
    const int w  = tid >> 6;
    const int l  = tid & 63;
    const int fr = l & 15;
    const int kg = l >> 4;

    // ---- S1a: fused score: 4 threads/edge, 8 heads each ----
    {
        const int row = tid >> 2;          // edge in tile
        const int j   = tid & 3;           // 24-float segment
        long long e = e0 + row;
        float q[24], k[24];
        if (e < E) {
            int dn = dst[e], sn = src[e];
            const float* qp = qkv + (size_t)dn * 288 + 24 * j;
            const float* kp = qkv + (size_t)sn * 288 + 96 + 24 * j;
            #pragma unroll
            for (int t = 0; t < 6; t++) {
                *(float4*)&q[t * 4] = *(const float4*)(qp + t * 4);
                *(float4*)&k[t * 4] = *(const float4*)(kp + t * 4);
            }
        } else {
            #pragma unroll
            for (int t = 0; t < 24; t++) { q[t] = 0.f; k[t] = 0.f; }
        }
        s16x8 qkb;
        #pragma unroll
        for (int t = 0; t < 8; t++) {
            float d = k[3*t]*q[3*t] + k[3*t+1]*q[3*t+1] + k[3*t+2]*q[3*t+2];
            qkb[t] = (short)f2b(0.5f * d);
        }
        *(s16x8*)&sQK[row * 40 + 8 * j] = qkb;
    }

    // ---- S1b: stage ev (f32), Wb|We^T (bf16), Wf1^T (bf16) ----
    #pragma unroll
    for (int rr = 0; rr < 2; rr++) {
        int idx = tid + 256 * rr;
        int row = idx >> 3, c4 = (idx & 7) * 4;
        long long e = e0 + row;
        float4 v = make_float4(0.f, 0.f, 0.f, 0.f);
        if (e < E) v = *(const float4*)(edge + e * 32 + c4);
        *(float4*)&sEV[row * 36 + c4] = v;
    }
    {
        int k = tid >> 3, c4 = (tid & 7) * 4;
        float4 vb = *(const float4*)(Wb + k * 32 + c4);
        float4 ve = *(const float4*)(We + k * 32 + c4);
        sB[(c4 + 0) * 40 + k] = f2b(vb.x); sB[(c4 + 1) * 40 + k] = f2b(vb.y);
        sB[(c4 + 2) * 40 + k] = f2b(vb.z); sB[(c4 + 3) * 40 + k] = f2b(vb.w);
        sB[(32 + c4 + 0) * 40 + k] = f2b(ve.x); sB[(32 + c4 + 1) * 40 + k] = f2b(ve.y);
        sB[(32 + c4 + 2) * 40 + k] = f2b(ve.z); sB[(32 + c4 + 3) * 40 + k] = f2b(ve.w);
    }
    #pragma unroll
    for (int rr = 0; rr < 2; rr++) {
        int idx = tid + 256 * rr;
        int k = idx >> 3, c4 = (idx & 7) * 4;
        float4 v = *(const float4*)(Wf1 + k * 32 + c4);
        sB2[(c4 + 0) * 72 + k] = f2b(v.x); sB2[(c4 + 1) * 72 + k] = f2b(v.y);
        sB2[(c4 + 2) * 72 + k] = f2b(v.z); sB2[(c4 + 3) * 72 + k] = f2b(v.w);
    }
    __syncthreads();

    // ---- S2: LN1 -> ew rows (bf16) in sA ----
    {
        const int row = 16 * w + (tid & 15);
        const int q = (tid & 63) >> 4;
        float x[8];
        *(float4*)&x[0] = *(float4*)&sEV[row * 36 + 8 * q];
        *(float4*)&x[4] = *(float4*)&sEV[row * 36 + 8 * q + 4];
        float s = x[0] + x[1] + x[2] + x[3] + x[4] + x[5] + x[6] + x[7];
        s += __shfl_xor(s, 16, 64); s += __shfl_xor(s, 32, 64);
        float mu = s * (1.f / 32.f);
        float v2 = 0.f;
        #pragma unroll
        for (int i = 0; i < 8; i++) { float d = x[i] - mu; v2 += d * d; }
        v2 += __shfl_xor(v2, 16, 64); v2 += __shfl_xor(v2, 32, 64);
        float rs = rsqrtf(v2 * (1.f / 32.f) + 1e-5f);
        float4 g1 = *(const float4*)(ge0 + 8 * q), g2 = *(const float4*)(ge0 + 8 * q + 4);
        float4 b1 = *(const float4*)(be0 + 8 * q), b2 = *(const float4*)(be0 + 8 * q + 4);
        float gg[8] = {g1.x, g1.y, g1.z, g1.w, g2.x, g2.y, g2.z, g2.w};
        float bs[8] = {b1.x, b1.y, b1.z, b1.w, b2.x, b2.y, b2.z, b2.w};
        s16x8 y;
        #pragma unroll
        for (int i = 0; i < 8; i++)
            y[i] = (short)f2b((x[i] - mu) * rs * gg[i] + bs[i]);
        *(s16x8*)&sA[row * 40 + 8 * q] = y;
    }
    __syncthreads();

    // ---- S3: GEMM1 (MFMA)  [64][64 = sc|veh] = ew @ [Wb|We] ----
    f32x4 acc[4];
    {
        s16x8 a = *(s16x8*)&sA[(16 * w + fr) * 40 + kg * 8];
        #pragma unroll
        for (int nt = 0; nt < 4; nt++) {
            s16x8 b = *(s16x8*)&sB[(16 * nt + fr) * 40 + kg * 8];
            f32x4 z = {0.f, 0.f, 0.f, 0.f};
            acc[nt] = __builtin_amdgcn_mfma_f32_16x16x32_bf16(a, b, z, 0, 0, 0);
        }
    }
    __syncthreads();

    // ---- S4: epilogue1 (exp -> sX; er -> sEV) + restage Wf0 -> sB ----
    #pragma unroll
    for (int nt = 0; nt < 2; nt++) {
        int col = nt * 16 + fr;
        float bbv = bb[col];
        #pragma unroll
        for (int r = 0; r < 4; r++) {
            int row = 16 * w + 4 * kg + r;
            float sc = acc[nt][r] + b2f(sQK[row * 40 + col]) + bbv;
            sX[row * 72 + col] = f2b(__expf(sc));
            float er = sc + sEV[row * 36 + col];
            sEV[row * 36 + col] = er;
        }
    }
    #pragma unroll
    for (int nt = 2; nt < 4; nt++) {
        int col = (nt - 2) * 16 + fr;
        float bev = be[col];
        #pragma unroll
        for (int r = 0; r < 4; r++) {
            int row = 16 * w + 4 * kg + r;
            sX[row * 72 + 32 + col] = f2b(acc[nt][r] + bev);
        }
    }
    #pragma unroll
    for (int rr = 0; rr < 2; rr++) {
        int idx = tid + 256 * rr;
        int k = idx >> 4, c4 = (idx & 15) * 4;
        float4 v = *(const float4*)(Wf0 + k * 64 + c4);
        sB[(c4 + 0) * 40 + k] = f2b(v.x); sB[(c4 + 1) * 40 + k] = f2b(v.y);
        sB[(c4 + 2) * 40 + k] = f2b(v.z); sB[(c4 + 3) * 40 + k] = f2b(v.w);
    }
    __syncthreads();

    // ---- S5: copy sX -> exve16 at CSR slot ; LN2 (er -> en bf16 in sA) ----
    #pragma unroll
    for (int rr = 0; rr < 2; rr++) {
        int idx = tid + 256 * rr;
        int row = idx >> 3, c8 = (idx & 7) * 8;
        long long e = e0 + row;
        if (e < E) {
            int p = pos[e];
            *(s16x8*)(exve16 + (size_t)p * 64 + c8) = *(s16x8*)&sX[row * 72 + c8];
        }
    }
    {
        const int row = 16 * w + (tid & 15);
        const int q = (tid & 63) >> 4;
        float x[8];
        *(float4*)&x[0] = *(float4*)&sEV[row * 36 + 8 * q];
        *(float4*)&x[4] = *(float4*)&sEV[row * 36 + 8 * q + 4];
        float s = x[0] + x[1] + x[2] + x[3] + x[4] + x[5] + x[6] + x[7];
        s += __shfl_xor(s, 16, 64); s += __shfl_xor(s, 32, 64);
        float mu = s * (1.f / 32.f);
        float v2 = 0.f;
        #pragma unroll
        for (int i = 0; i < 8; i++) { float d = x[i] - mu; v2 += d * d; }
        v2 += __shfl_xor(v2, 16, 64); v2 += __shfl_xor(v2, 32, 64);
        float rs = rsqrtf(v2 * (1.f / 32.f) + 1e-5f);
        float4 g1 = *(const float4*)(ge1 + 8 * q), g2 = *(const float4*)(ge1 + 8 * q + 4);
        float4 b1 = *(const float4*)(be1 + 8 * q), b2 = *(const float4*)(be1 + 8 * q + 4);
        float gg[8] = {g1.x, g1.y, g1.z, g1.w, g2.x, g2.y, g2.z, g2.w};
        float bs[8] = {b1.x, b1.y, b1.z, b1.w, b2.x, b2.y, b2.z, b2.w};
        s16x8 y;
        #pragma unroll
        for (int i = 0; i < 8; i++)
            y[i] = (short)f2b((x[i] - mu) * rs * gg[i] + bs[i]);
        *(s16x8*)&sA[row * 40 + 8 * q] = y;
    }
    __syncthreads();

    // ---- S6: GEMM2 (MFMA)  F[64][64] = relu(en @ Wf0 + bf0) -> sX rows ----
    {
        s16x8 a = *(s16x8*)&sA[(16 * w + fr) * 40 + kg * 8];
        #pragma unroll
        for (int nt = 0; nt < 4; nt++) {
            s16x8 b = *(s16x8*)&sB[(16 * nt + fr) * 40 + kg * 8];
            f32x4 z = {0.f, 0.f, 0.f, 0.f};
            f32x4 a2 = __builtin_amdgcn_mfma_f32_16x16x32_bf16(a, b, z, 0, 0, 0);
            int col = nt * 16 + fr;
            float b0v = bf0[col];
            #pragma unroll
            for (int r = 0; r < 4; r++) {
                int row = 16 * w + 4 * kg + r;
                sX[row * 72 + col] = f2b(fmaxf(a2[r] + b0v, 0.f));
            }
        }
    }
    __syncthreads();

    // ---- S7: GEMM3 (MFMA)  out[64][32] = F @ Wf1 + er + bf1 -> sEV ----
    {
        s16x8 a0 = *(s16x8*)&sX[(16 * w + fr) * 72 + kg * 8];
        s16x8 a1 = *(s16x8*)&sX[(16 * w + fr) * 72 + 32 + kg * 8];
        #pragma unroll
        for (int nt = 0; nt < 2; nt++) {
            s16x8 b0 = *(s16x8*)&sB2[(16 * nt + fr) * 72 + kg * 8];
            s16x8 b1 = *(s16x8*)&sB2[(16 * nt + fr) * 72 + 32 + kg * 8];
            f32x4 z = {0.f, 0.f, 0.f, 0.f};
            f32x4 t = __builtin_amdgcn_mfma_f32_16x16x32_bf16(a0, b0, z, 0, 0, 0);
            t = __builtin_amdgcn_mfma_f32_16x16x32_bf16(a1, b1, t, 0, 0, 0);
            int col = nt * 16 + fr;
            float bf1v = bf1[col];
            #pragma unroll
            for (int r = 0; r < 4; r++) {
                int row = 16 * w + 4 * kg + r;
                float out = t[r] + sEV[row * 36 + col] + bf1v;
                sEV[row * 36 + col] = out;
            }
        }
    }
    __syncthreads();

    // ---- S8: copy sEV[:, 0..32) -> eout ----
    #pragma unroll
    for (int rr = 0; rr < 2; rr++) {
        int idx = tid + 256 * rr;
        int row = idx >> 3, c4 = (idx & 7) * 4;
        long long e = e0 + row;
        if (e < E)
            *(float4*)(eout + e * 32 + c4) = *(float4*)&sEV[row * 36 + c4];
    }
}

// ---------------- gather: one wave per node; contiguous CSR reads ----------
__global__ __launch_bounds__(256) void gather_kernel(
    const unsigned short* __restrict__ exve16, const float* __restrict__ qkv,
    const int* __restrict__ srcs, const int* __restrict__ off,
    const int* __restrict__ cnt, float* __restrict__ agg, int N)
{
    __shared__ float sV[4][2][96];
    __shared__ unsigned short sE16[4][2][64];
    const int wave = threadIdx.x >> 6;
    const int lane = threadIdx.x & 63;
    const int head = lane & 31;
    const int half = lane >> 5;
    int n = blockIdx.x * 4 + wave;
    if (n >= N) return;
    const int o = off[n], d = cnt[n];
    float a0 = 0.f, a1 = 0.f, a2 = 0.f, a3 = 0.f, den = 0.f;
    for (int i = half; i < d; i += 2) {
        int sn = srcs[o + i];
        const float* vr = qkv + (size_t)sn * 288 + 192;
        const unsigned short* er = exve16 + (size_t)(o + i) * 64;
        if (head < 24) {
            *(float4*)&sV[wave][half][head * 4] = *(const float4*)(vr + head * 4);
        } else {
            int j = head - 24;
            *(s16x8*)&sE16[wave][half][j * 8] = *(const s16x8*)(er + j * 8);
        }
        __builtin_amdgcn_wave_barrier();
        float ex = b2f(sE16[wave][half][head]);
        float vv = b2f(sE16[wave][half][32 + head]);
        a0 += ex * sV[wave][half][head * 3];
        a1 += ex * sV[wave][half][head * 3 + 1];
        a2 += ex * sV[wave][half][head * 3 + 2];
        a3 += ex * vv;
        den += ex;
        __builtin_amdgcn_wave_barrier();
    }
    a0 += __shfl_xor(a0, 32, 64);
    a1 += __shfl_xor(a1, 32, 64);
    a2 += __shfl_xor(a2, 32, 64);
    a3 += __shfl_xor(a3, 32, 64);
    den += __shfl_xor(den, 32, 64);
    if (half == 0) {
        float sc = (d > 0) ? 1.f / den : 0.f;
        float* ap = agg + (size_t)n * 128 + head * 4;
        ap[0] = a0 * sc; ap[1] = a1 * sc; ap[2] = a2 * sc; ap[3] = a3 * sc;
    }
}

// ---------------------------------------------------------------------------
extern "C" void kernel_launch(void* const* d_in, const int* in_sizes, int n_in,
                              void* d_out, int out_size, void* d_ws, size_t ws_size,
                              hipStream_t stream)
{
    (void)n_in; (void)out_size; (void)ws_size;
    const float* feat = (const float*)d_in[0];
    const float* edge = (const float*)d_in[1];
    const float* Wq   = (const float*)d_in[2];
    const float* bq   = (const float*)d_in[3];
    const float* Wk   = (const float*)d_in[4];
    const float* bk   = (const float*)d_in[5];
    const float* Wv   = (const float*)d_in[6];
    const float* bv   = (const float*)d_in[7];
    const float* We   = (const float*)d_in[8];
    const float* be   = (const float*)d_in[9];
    const float* Wb   = (const float*)d_in[10];
    const float* bb   = (const float*)d_in[11];
    const float* Wvv  = (const float*)d_in[12];
    const float* bvv  = (const float*)d_in[13];
    const float* Wf0  = (const float*)d_in[14];
    const float* bf0  = (const float*)d_in[15];
    const float* Wf1  = (const float*)d_in[16];
    const float* bf1  = (const float*)d_in[17];
    const float* Wm0  = (const float*)d_in[18];
    const float* bm0  = (const float*)d_in[19];
    const float* Wm1  = (const float*)d_in[20];
    const float* bm1  = (const float*)d_in[21];
    const float* g_n0 = (const float*)d_in[22];
    const float* b_n0 = (const float*)d_in[23];
    const float* g_e0 = (const float*)d_in[24];
    const float* b_e0 = (const float*)d_in[25];
    const float* g_e1 = (const float*)d_in[26];
    const float* b_e1 = (const float*)d_in[27];
    const float* g_m  = (const float*)d_in[28];
    const float* b_m  = (const float*)d_in[29];
    const float* wsc  = (const float*)d_in[30];
    const int*   src  = (const int*)d_in[31];
    const int*   dst  = (const int*)d_in[32];

    const int N = in_sizes[0] / 96;
    const int E = in_sizes[1] / 32;

    float* ws    = (float*)d_ws;
    float* qkv   = ws;                                      // N*288 f32
    float* agg   = qkv + (size_t)N * 288;                   // N*128 f32
    float* h0    = agg + (size_t)N * 128;                   // N*96 f32
    float* hp    = h0 + (size_t)N * 96;                     // N*96 f32
    unsigned short* exve16 = (unsigned short*)(hp + (size_t)N * 96); // E*64 bf16
    int*   pos   = (int*)(exve16 + (size_t)E * 64);         // E
    int*   srcs  = pos + E;                                 // E
    int*   cnt   = srcs + E;                                // N
    int*   offv  = cnt + N;                                 // N
    int*   cur   = offv + N;                                // N
    float* tbuf  = ws;                                      // N*192, reuses qkv late
    float* hout  = (float*)d_out;
    float* eoutp = (float*)d_out + (size_t)N * 96;

    hipMemsetAsync(cnt, 0, (size_t)N * sizeof(int), stream);

    const int mt = (N + 63) / 64;
    const int et = (E + 255) / 256;

    // CSR bucketing
    count_kernel<<<et, 256, 0, stream>>>(dst, cnt, E);
    scan_kernel<<<1, 1024, 0, stream>>>(cnt, offv, cur, N);
    scatter_kernel<<<et, 256, 0, stream>>>(dst, src, cur, pos, srcs, E);

    // node side: h0 = LN(feat); qkv = h0 @ [Wq|Wk|Wv]
    ln96_kernel<<<(N + 7) / 8, 256, 0, stream>>>(feat, g_n0, b_n0, h0, N);
    gemm_kernel<0,0><<<dim3(mt, 2), 192, 0, stream>>>(h0, 96, Wq, 96, bq, nullptr, nullptr, qkv, 288, 0,   N, 96);
    gemm_kernel<0,0><<<dim3(mt, 2), 192, 0, stream>>>(h0, 96, Wk, 96, bk, nullptr, nullptr, qkv, 288, 96,  N, 96);
    gemm_kernel<0,0><<<dim3(mt, 2), 192, 0, stream>>>(h0, 96, Wv, 96, bv, nullptr, nullptr, qkv, 288, 192, N, 96);

    // fused edge tile pass (computes qk in-kernel, writes exve16 + e-out)
    edge_tile_kernel<<<(E + 63) / 64, 256, 0, stream>>>(edge, qkv, src, dst, pos,
                                             We, be, Wb, bb, Wf0, bf0, Wf1, bf1,
                                             g_e0, b_e0, g_e1, b_e1,
                                             exve16, eoutp, E);

    // gather per node -> normalized agg[N,128]  (contiguous CSR reads)
    gather_kernel<<<(N + 3) / 4, 256, 0, stream>>>(exve16, qkv, srcs, offv, cnt, agg, N);

    // h_pre = feat*(1+w) + agg @ Wvv + bvv
    gemm_kernel<0,1><<<dim3(mt, 2), 192, 0, stream>>>(agg, 128, Wvv, 96, bvv, feat, wsc, hp, 96, 0, N, 128);
    // hn = LN(h_pre)
    ln96_kernel<<<(N + 7) / 8, 256, 0, stream>>>(hp, g_m, b_m, h0, N);
    // t = relu(hn @ Wm0 + bm0)
    gemm_kernel<1,0><<<dim3(mt, 4), 192, 0, stream>>>(h0, 96, Wm0, 192, bm0, nullptr, nullptr, tbuf, 192, 0, N, 96);
    // h_out = h_pre + t @ Wm1 + bm1
    gemm_kernel<0,1><<<dim3(mt, 2), 192, 0, stream>>>(tbuf, 192, Wm1, 96, bm1, hp, nullptr, hout, 96, 0, N, 192);
}

// Round 12
// 949.570 us; speedup vs baseline: 2.1902x; 1.1153x over previous
//
#include <hip/hip_runtime.h>
#include <cstdint>
#include <cstddef>

// ---------------------------------------------------------------------------
// EGT layer.  N nodes (DIM=96, H=32, HD=3), E edges.
// edge_tile_kernel: 64-edge tile per block, qk in-kernel, MFMA bf16 GEMMs.
// mgemm_kernel: MFMA bf16 node-side GEMM (BM=64, BN=96, K-chunk 32);
// MULTI mode runs q|k|v in one launch and emits bf16 v16 for gather.
// CSR-ordered exve so gather reads are contiguous.
// ---------------------------------------------------------------------------

typedef short  s16x8 __attribute__((ext_vector_type(8)));
typedef float  f32x4 __attribute__((ext_vector_type(4)));

__device__ __forceinline__ unsigned short f2b(float x) {
    union { float f; unsigned u; } v; v.f = x;
    unsigned r = v.u + 0x7FFF + ((v.u >> 16) & 1);   // RNE
    return (unsigned short)(r >> 16);
}
__device__ __forceinline__ float b2f(unsigned short u) {
    union { unsigned u; float f; } v; v.u = ((unsigned)u) << 16; return v.f;
}

__device__ __forceinline__ float red32(float v) {
    #pragma unroll
    for (int m = 16; m >= 1; m >>= 1) v += __shfl_xor(v, m, 64);
    return v;
}

// ---------------- row LayerNorm over D=96 ----------------
__global__ __launch_bounds__(256) void ln96_kernel(
    const float* __restrict__ x, const float* __restrict__ g,
    const float* __restrict__ b, float* __restrict__ y, int M)
{
    int lane = threadIdx.x & 31;
    int grp  = threadIdx.x >> 5;
    int r = blockIdx.x * 8 + grp;
    if (r >= M) return;
    const float* xr = x + (size_t)r * 96;
    float a0 = xr[lane], a1 = xr[lane + 32], a2 = xr[lane + 64];
    float mu = red32(a0 + a1 + a2) * (1.f / 96.f);
    float d0 = a0 - mu, d1 = a1 - mu, d2 = a2 - mu;
    float var = red32(d0 * d0 + d1 * d1 + d2 * d2) * (1.f / 96.f);
    float rs = rsqrtf(var + 1e-5f);
    float* yr = y + (size_t)r * 96;
    yr[lane]      = d0 * rs * g[lane]      + b[lane];
    yr[lane + 32] = d1 * rs * g[lane + 32] + b[lane + 32];
    yr[lane + 64] = d2 * rs * g[lane + 64] + b[lane + 64];
}

// ---------------- MFMA node GEMM: C[M,*] = A[M,K] @ B[K,96-chunk] ----------
// MULTI: blockIdx.y selects {B0,B1,B2} (q|k|v), C col offset = y*96; the
// y==2 (v) pass also writes bf16 copy C16[M][96].
// else: blockIdx.y is a 96-wide N-chunk of a single B (col offset y*96).
template<int MULTI, int RELU, int RES>
__global__ __launch_bounds__(256) void mgemm_kernel(
    const float* __restrict__ A, int lda,
    const float* __restrict__ B0, const float* __restrict__ B1,
    const float* __restrict__ B2, int ldb,
    const float* __restrict__ bias0, const float* __restrict__ bias1,
    const float* __restrict__ bias2,
    const float* __restrict__ resid,
    const float* __restrict__ wptr,
    float* __restrict__ C, int ldc,
    unsigned short* __restrict__ C16,
    int M, int K)
{
    __shared__ unsigned short sA[64 * 40];   // A chunk bf16 [64][32]
    __shared__ unsigned short sB[96 * 40];   // B^T chunk bf16 [96][32]

    const int tid = threadIdx.x;
    const int m0 = blockIdx.x * 64;
    const int y  = blockIdx.y;
    const float* B = MULTI ? (y == 0 ? B0 : (y == 1 ? B1 : B2)) : B0;
    const int nbB = MULTI ? 0 : y * 96;      // B col offset
    const int nbC = y * 96;                  // C col offset

    const int w = tid >> 6, l = tid & 63, fr = l & 15, kg = l >> 4;

    f32x4 acc[6];
    #pragma unroll
    for (int i = 0; i < 6; i++) acc[i] = (f32x4){0.f, 0.f, 0.f, 0.f};

    for (int kc = 0; kc < K; kc += 32) {
        {
            int row = tid >> 2, k8 = (tid & 3) * 8;
            int grow = m0 + row;
            s16x8 a8 = {0, 0, 0, 0, 0, 0, 0, 0};
            if (grow < M) {
                float4 v0 = *(const float4*)(A + (size_t)grow * lda + kc + k8);
                float4 v1 = *(const float4*)(A + (size_t)grow * lda + kc + k8 + 4);
                a8[0] = (short)f2b(v0.x); a8[1] = (short)f2b(v0.y);
                a8[2] = (short)f2b(v0.z); a8[3] = (short)f2b(v0.w);
                a8[4] = (short)f2b(v1.x); a8[5] = (short)f2b(v1.y);
                a8[6] = (short)f2b(v1.z); a8[7] = (short)f2b(v1.w);
            }
            *(s16x8*)&sA[row * 40 + k8] = a8;
        }
        #pragma unroll
        for (int r = 0; r < 3; r++) {
            int idx = tid + 256 * r;          // 0..767
            int k = idx / 24;                 // 0..31
            int n4 = (idx - k * 24) * 4;      // 0..92
            float4 v = *(const float4*)(B + (size_t)(kc + k) * ldb + nbB + n4);
            sB[(n4 + 0) * 40 + k] = f2b(v.x);
            sB[(n4 + 1) * 40 + k] = f2b(v.y);
            sB[(n4 + 2) * 40 + k] = f2b(v.z);
            sB[(n4 + 3) * 40 + k] = f2b(v.w);
        }
        __syncthreads();
        {
            s16x8 a = *(s16x8*)&sA[(16 * w + fr) * 40 + kg * 8];
            #pragma unroll
            for (int nt = 0; nt < 6; nt++) {
                s16x8 b = *(s16x8*)&sB[(16 * nt + fr) * 40 + kg * 8];
                acc[nt] = __builtin_amdgcn_mfma_f32_16x16x32_bf16(a, b, acc[nt], 0, 0, 0);
            }
        }
        __syncthreads();
    }

    float scale = 1.f;
    if (RES) scale = wptr ? (1.f + wptr[0]) : 1.f;
    const float* biasp = MULTI ? (y == 0 ? bias0 : (y == 1 ? bias1 : bias2)) : bias0;
    const int bbase = MULTI ? 0 : nbB;

    #pragma unroll
    for (int nt = 0; nt < 6; nt++) {
        int cl = nt * 16 + fr;
        float bv = biasp[bbase + cl];
        int gcol = nbC + cl;
        #pragma unroll
        for (int r = 0; r < 4; r++) {
            int row = m0 + 16 * w + 4 * kg + r;
            if (row >= M) continue;
            float v = acc[nt][r] + bv;
            if (RELU) v = fmaxf(v, 0.f);
            if (RES) v += scale * resid[(size_t)row * ldc + gcol];
            C[(size_t)row * ldc + gcol] = v;
            if (MULTI && C16 != nullptr && y == 2)
                C16[(size_t)row * 96 + cl] = f2b(v);
        }
    }
}

// ---------------- CSR bucketing ----------------
__global__ __launch_bounds__(256) void count_kernel(
    const int* __restrict__ dst, int* __restrict__ cnt, int E)
{
    int i = blockIdx.x * 256 + threadIdx.x;
    if (i < E) atomicAdd(&cnt[dst[i]], 1);
}

__global__ __launch_bounds__(1024) void scan_kernel(
    const int* __restrict__ cnt, int* __restrict__ off, int* __restrict__ cur, int N)
{
    __shared__ int s[1024];
    const int tid = threadIdx.x;
    const int chunk = (N + 1023) >> 10;
    const int lo = tid * chunk;
    const int hi = min(lo + chunk, N);
    int sum = 0;
    for (int i = lo; i < hi; i++) sum += cnt[i];
    s[tid] = sum;
    __syncthreads();
    for (int d = 1; d < 1024; d <<= 1) {
        int v = (tid >= d) ? s[tid - d] : 0;
        __syncthreads();
        s[tid] += v;
        __syncthreads();
    }
    int base = (tid == 0) ? 0 : s[tid - 1];
    for (int i = lo; i < hi; i++) {
        off[i] = base; cur[i] = base;
        base += cnt[i];
    }
}

__global__ __launch_bounds__(256) void scatter_kernel(
    const int* __restrict__ dst, const int* __restrict__ src,
    int* __restrict__ cur, int* __restrict__ pos, int* __restrict__ srcs, int E)
{
    int i = blockIdx.x * 256 + threadIdx.x;
    if (i < E) {
        int p = atomicAdd(&cur[dst[i]], 1);
        pos[i] = p;
        srcs[p] = src[i];
    }
}

// ---------------- edge tile kernel: 64 edges per block, MFMA GEMMs ----------
__global__ __launch_bounds__(256, 4) void edge_tile_kernel(
    const float* __restrict__ edge, const float* __restrict__ qkv,
    const int* __restrict__ src, const int* __restrict__ dst,
    const int* __restrict__ pos,
    const float* __restrict__ We, const float* __restrict__ be,
    const float* __restrict__ Wb, const float* __restrict__ bb,
    const float* __restrict__ Wf0, const float* __restrict__ bf0,
    const float* __restrict__ Wf1, const float* __restrict__ bf1,
    const float* __restrict__ ge0, const float* __restrict__ be0,
    const float* __restrict__ ge1, const float* __restrict__ be1,
    unsigned short* __restrict__ exve16, float* __restrict__ eout, int E)
{
    __shared__ float          sEV[64 * 36];
    __shared__ unsigned short sQK[64 * 40];
    __shared__ unsigned short sA [64 * 40];
    __shared__ unsigned short sB [64 * 40];
    __shared__ unsigned short sB2[32 * 72];
    __shared__ unsigned short sX [64 * 72];

    const int tid = threadIdx.x;
    const long long e0 = (long long)blockIdx.x * 64;
    const int w  = tid >> 6;
    const int l  = tid & 63;
    const int fr = l & 15;
    const int kg = l >> 4;

    // ---- S1a: fused score: 4 threads/edge, 8 heads each ----
    {
        const int row = tid >> 2;
        const int j   = tid & 3;
        long long e = e0 + row;
        float q[24], k[24];
        if (e < E) {
            int dn = dst[e], sn = src[e];
            const float* qp = qkv + (size_t)dn * 288 + 24 * j;
            const float* kp = qkv + (size_t)sn * 288 + 96 + 24 * j;
            #pragma unroll
            for (int t = 0; t < 6; t++) {
                *(float4*)&q[t * 4] = *(const float4*)(qp + t * 4);
                *(float4*)&k[t * 4] = *(const float4*)(kp + t * 4);
            }
        } else {
            #pragma unroll
            for (int t = 0; t < 24; t++) { q[t] = 0.f; k[t] = 0.f; }
        }
        s16x8 qkb;
        #pragma unroll
        for (int t = 0; t < 8; t++) {
            float d = k[3*t]*q[3*t] + k[3*t+1]*q[3*t+1] + k[3*t+2]*q[3*t+2];
            qkb[t] = (short)f2b(0.5f * d);
        }
        *(s16x8*)&sQK[row * 40 + 8 * j] = qkb;
    }

    // ---- S1b: stage ev (f32), Wb|We^T (bf16), Wf1^T (bf16) ----
    #pragma unroll
    for (int rr = 0; rr < 2; rr++) {
        int idx = tid + 256 * rr;
        int row = idx >> 3, c4 = (idx & 7) * 4;
        long long e = e0 + row;
        float4 v = make_float4(0.f, 0.f, 0.f, 0.f);
        if (e < E) v = *(const float4*)(edge + e * 32 + c4);
        *(float4*)&sEV[row * 36 + c4] = v;
    }
    {
        int k = tid >> 3, c4 = (tid & 7) * 4;
        float4 vb = *(const float4*)(Wb + k * 32 + c4);
        float4 ve = *(const float4*)(We + k * 32 + c4);
        sB[(c4 + 0) * 40 + k] = f2b(vb.x); sB[(c4 + 1) * 40 + k] = f2b(vb.y);
        sB[(c4 + 2) * 40 + k] = f2b(vb.z); sB[(c4 + 3) * 40 + k] = f2b(vb.w);
        sB[(32 + c4 + 0) * 40 + k] = f2b(ve.x); sB[(32 + c4 + 1) * 40 + k] = f2b(ve.y);
        sB[(32 + c4 + 2) * 40 + k] = f2b(ve.z); sB[(32 + c4 + 3) * 40 + k] = f2b(ve.w);
    }
    #pragma unroll
    for (int rr = 0; rr < 2; rr++) {
        int idx = tid + 256 * rr;
        int k = idx >> 3, c4 = (idx & 7) * 4;
        float4 v = *(const float4*)(Wf1 + k * 32 + c4);
        sB2[(c4 + 0) * 72 + k] = f2b(v.x); sB2[(c4 + 1) * 72 + k] = f2b(v.y);
        sB2[(c4 + 2) * 72 + k] = f2b(v.z); sB2[(c4 + 3) * 72 + k] = f2b(v.w);
    }
    __syncthreads();

    // ---- S2: LN1 -> ew rows (bf16) in sA ----
    {
        const int row = 16 * w + (tid & 15);
        const int q = (tid & 63) >> 4;
        float x[8];
        *(float4*)&x[0] = *(float4*)&sEV[row * 36 + 8 * q];
        *(float4*)&x[4] = *(float4*)&sEV[row * 36 + 8 * q + 4];
        float s = x[0] + x[1] + x[2] + x[3] + x[4] + x[5] + x[6] + x[7];
        s += __shfl_xor(s, 16, 64); s += __shfl_xor(s, 32, 64);
        float mu = s * (1.f / 32.f);
        float v2 = 0.f;
        #pragma unroll
        for (int i = 0; i < 8; i++) { float d = x[i] - mu; v2 += d * d; }
        v2 += __shfl_xor(v2, 16, 64); v2 += __shfl_xor(v2, 32, 64);
        float rs = rsqrtf(v2 * (1.f / 32.f) + 1e-5f);
        float4 g1 = *(const float4*)(ge0 + 8 * q), g2 = *(const float4*)(ge0 + 8 * q + 4);
        float4 b1 = *(const float4*)(be0 + 8 * q), b2 = *(const float4*)(be0 + 8 * q + 4);
        float gg[8] = {g1.x, g1.y, g1.z, g1.w, g2.x, g2.y, g2.z, g2.w};
        float bs[8] = {b1.x, b1.y, b1.z, b1.w, b2.x, b2.y, b2.z, b2.w};
        s16x8 y;
        #pragma unroll
        for (int i = 0; i < 8; i++)
            y[i] = (short)f2b((x[i] - mu) * rs * gg[i] + bs[i]);
        *(s16x8*)&sA[row * 40 + 8 * q] = y;
    }
    __syncthreads();

    // ---- S3: GEMM1 (MFMA)  [64][64 = sc|veh] = ew @ [Wb|We] ----
    f32x4 acc[4];
    {
        s16x8 a = *(s16x8*)&sA[(16 * w + fr) * 40 + kg * 8];
        #pragma unroll
        for (int nt = 0; nt < 4; nt++) {
            s16x8 b = *(s16x8*)&sB[(16 * nt + fr) * 40 + kg * 8];
            f32x4 z = {0.f, 0.f, 0.f, 0.f};
            acc[nt] = __builtin_amdgcn_mfma_f32_16x16x32_bf16(a, b, z, 0, 0, 0);
        }
    }
    __syncthreads();

    // ---- S4: epilogue1 (exp -> sX; er -> sEV) + restage Wf0 -> sB ----
    #pragma unroll
    for (int nt = 0; nt < 2; nt++) {
        int col = nt * 16 + fr;
        float bbv = bb[col];
        #pragma unroll
        for (int r = 0; r < 4; r++) {
            int row = 16 * w + 4 * kg + r;
            float sc = acc[nt][r] + b2f(sQK[row * 40 + col]) + bbv;
            sX[row * 72 + col] = f2b(__expf(sc));
            float er = sc + sEV[row * 36 + col];
            sEV[row * 36 + col] = er;
        }
    }
    #pragma unroll
    for (int nt = 2; nt < 4; nt++) {
        int col = (nt - 2) * 16 + fr;
        float bev = be[col];
        #pragma unroll
        for (int r = 0; r < 4; r++) {
            int row = 16 * w + 4 * kg + r;
            sX[row * 72 + 32 + col] = f2b(acc[nt][r] + bev);
        }
    }
    #pragma unroll
    for (int rr = 0; rr < 2; rr++) {
        int idx = tid + 256 * rr;
        int k = idx >> 4, c4 = (idx & 15) * 4;
        float4 v = *(const float4*)(Wf0 + k * 64 + c4);
        sB[(c4 + 0) * 40 + k] = f2b(v.x); sB[(c4 + 1) * 40 + k] = f2b(v.y);
        sB[(c4 + 2) * 40 + k] = f2b(v.z); sB[(c4 + 3) * 40 + k] = f2b(v.w);
    }
    __syncthreads();

    // ---- S5: copy sX -> exve16 at CSR slot ; LN2 (er -> en bf16 in sA) ----
    #pragma unroll
    for (int rr = 0; rr < 2; rr++) {
        int idx = tid + 256 * rr;
        int row = idx >> 3, c8 = (idx & 7) * 8;
        long long e = e0 + row;
        if (e < E) {
            int p = pos[e];
            *(s16x8*)(exve16 + (size_t)p * 64 + c8) = *(s16x8*)&sX[row * 72 + c8];
        }
    }
    {
        const int row = 16 * w + (tid & 15);
        const int q = (tid & 63) >> 4;
        float x[8];
        *(float4*)&x[0] = *(float4*)&sEV[row * 36 + 8 * q];
        *(float4*)&x[4] = *(float4*)&sEV[row * 36 + 8 * q + 4];
        float s = x[0] + x[1] + x[2] + x[3] + x[4] + x[5] + x[6] + x[7];
        s += __shfl_xor(s, 16, 64); s += __shfl_xor(s, 32, 64);
        float mu = s * (1.f / 32.f);
        float v2 = 0.f;
        #pragma unroll
        for (int i = 0; i < 8; i++) { float d = x[i] - mu; v2 += d * d; }
        v2 += __shfl_xor(v2, 16, 64); v2 += __shfl_xor(v2, 32, 64);
        float rs = rsqrtf(v2 * (1.f / 32.f) + 1e-5f);
        float4 g1 = *(const float4*)(ge1 + 8 * q), g2 = *(const float4*)(ge1 + 8 * q + 4);
        float4 b1 = *(const float4*)(be1 + 8 * q), b2 = *(const float4*)(be1 + 8 * q + 4);
        float gg[8] = {g1.x, g1.y, g1.z, g1.w, g2.x, g2.y, g2.z, g2.w};
        float bs[8] = {b1.x, b1.y, b1.z, b1.w, b2.x, b2.y, b2.z, b2.w};
        s16x8 y;
        #pragma unroll
        for (int i = 0; i < 8; i++)
            y[i] = (short)f2b((x[i] - mu) * rs * gg[i] + bs[i]);
        *(s16x8*)&sA[row * 40 + 8 * q] = y;
    }
    __syncthreads();

    // ---- S6: GEMM2 (MFMA)  F[64][64] = relu(en @ Wf0 + bf0) -> sX rows ----
    {
        s16x8 a = *(s16x8*)&sA[(16 * w + fr) * 40 + kg * 8];
        #pragma unroll
        for (int nt = 0; nt < 4; nt++) {
            s16x8 b = *(s16x8*)&sB[(16 * nt + fr) * 40 + kg * 8];
            f32x4 z = {0.f, 0.f, 0.f, 0.f};
            f32x4 a2 = __builtin_amdgcn_mfma_f32_16x16x32_bf16(a, b, z, 0, 0, 0);
            int col = nt * 16 + fr;
            float b0v = bf0[col];
            #pragma unroll
            for (int r = 0; r < 4; r++) {
                int row = 16 * w + 4 * kg + r;
                sX[row * 72 + col] = f2b(fmaxf(a2[r] + b0v, 0.f));
            }
        }
    }
    __syncthreads();

    // ---- S7: GEMM3 (MFMA)  out[64][32] = F @ Wf1 + er + bf1 -> sEV ----
    {
        s16x8 a0 = *(s16x8*)&sX[(16 * w + fr) * 72 + kg * 8];
        s16x8 a1 = *(s16x8*)&sX[(16 * w + fr) * 72 + 32 + kg * 8];
        #pragma unroll
        for (int nt = 0; nt < 2; nt++) {
            s16x8 b0 = *(s16x8*)&sB2[(16 * nt + fr) * 72 + kg * 8];
            s16x8 b1 = *(s16x8*)&sB2[(16 * nt + fr) * 72 + 32 + kg * 8];
            f32x4 z = {0.f, 0.f, 0.f, 0.f};
            f32x4 t = __builtin_amdgcn_mfma_f32_16x16x32_bf16(a0, b0, z, 0, 0, 0);
            t = __builtin_amdgcn_mfma_f32_16x16x32_bf16(a1, b1, t, 0, 0, 0);
            int col = nt * 16 + fr;
            float bf1v = bf1[col];
            #pragma unroll
            for (int r = 0; r < 4; r++) {
                int row = 16 * w + 4 * kg + r;
                float out = t[r] + sEV[row * 36 + col] + bf1v;
                sEV[row * 36 + col] = out;
            }
        }
    }
    __syncthreads();

    // ---- S8: copy sEV[:, 0..32) -> eout ----
    #pragma unroll
    for (int rr = 0; rr < 2; rr++) {
        int idx = tid + 256 * rr;
        int row = idx >> 3, c4 = (idx & 7) * 4;
        long long e = e0 + row;
        if (e < E)
            *(float4*)(eout + e * 32 + c4) = *(float4*)&sEV[row * 36 + c4];
    }
}

// ---------------- gather: one wave per node; contiguous CSR + bf16 v ------
__global__ __launch_bounds__(256) void gather_kernel(
    const unsigned short* __restrict__ exve16, const unsigned short* __restrict__ v16,
    const int* __restrict__ srcs, const int* __restrict__ off,
    const int* __restrict__ cnt, float* __restrict__ agg, int N)
{
    __shared__ unsigned short sV16[4][2][96];
    __shared__ unsigned short sE16[4][2][64];
    const int wave = threadIdx.x >> 6;
    const int lane = threadIdx.x & 63;
    const int head = lane & 31;
    const int half = lane >> 5;
    int n = blockIdx.x * 4 + wave;
    if (n >= N) return;
    const int o = off[n], d = cnt[n];
    float a0 = 0.f, a1 = 0.f, a2 = 0.f, a3 = 0.f, den = 0.f;
    for (int i = half; i < d; i += 2) {
        int sn = srcs[o + i];
        const unsigned short* vr = v16 + (size_t)sn * 96;
        const unsigned short* er = exve16 + (size_t)(o + i) * 64;
        if (head < 12) {
            *(s16x8*)&sV16[wave][half][head * 8] = *(const s16x8*)(vr + head * 8);
        } else if (head >= 24) {
            int j = head - 24;
            *(s16x8*)&sE16[wave][half][j * 8] = *(const s16x8*)(er + j * 8);
        }
        __builtin_amdgcn_wave_barrier();
        float ex = b2f(sE16[wave][half][head]);
        float vv = b2f(sE16[wave][half][32 + head]);
        a0 += ex * b2f(sV16[wave][half][head * 3]);
        a1 += ex * b2f(sV16[wave][half][head * 3 + 1]);
        a2 += ex * b2f(sV16[wave][half][head * 3 + 2]);
        a3 += ex * vv;
        den += ex;
        __builtin_amdgcn_wave_barrier();
    }
    a0 += __shfl_xor(a0, 32, 64);
    a1 += __shfl_xor(a1, 32, 64);
    a2 += __shfl_xor(a2, 32, 64);
    a3 += __shfl_xor(a3, 32, 64);
    den += __shfl_xor(den, 32, 64);
    if (half == 0) {
        float sc = (d > 0) ? 1.f / den : 0.f;
        float* ap = agg + (size_t)n * 128 + head * 4;
        ap[0] = a0 * sc; ap[1] = a1 * sc; ap[2] = a2 * sc; ap[3] = a3 * sc;
    }
}

// ---------------------------------------------------------------------------
extern "C" void kernel_launch(void* const* d_in, const int* in_sizes, int n_in,
                              void* d_out, int out_size, void* d_ws, size_t ws_size,
                              hipStream_t stream)
{
    (void)n_in; (void)out_size; (void)ws_size;
    const float* feat = (const float*)d_in[0];
    const float* edge = (const float*)d_in[1];
    const float* Wq   = (const float*)d_in[2];
    const float* bq   = (const float*)d_in[3];
    const float* Wk   = (const float*)d_in[4];
    const float* bk   = (const float*)d_in[5];
    const float* Wv   = (const float*)d_in[6];
    const float* bv   = (const float*)d_in[7];
    const float* We   = (const float*)d_in[8];
    const float* be   = (const float*)d_in[9];
    const float* Wb   = (const float*)d_in[10];
    const float* bb   = (const float*)d_in[11];
    const float* Wvv  = (const float*)d_in[12];
    const float* bvv  = (const float*)d_in[13];
    const float* Wf0  = (const float*)d_in[14];
    const float* bf0  = (const float*)d_in[15];
    const float* Wf1  = (const float*)d_in[16];
    const float* bf1  = (const float*)d_in[17];
    const float* Wm0  = (const float*)d_in[18];
    const float* bm0  = (const float*)d_in[19];
    const float* Wm1  = (const float*)d_in[20];
    const float* bm1  = (const float*)d_in[21];
    const float* g_n0 = (const float*)d_in[22];
    const float* b_n0 = (const float*)d_in[23];
    const float* g_e0 = (const float*)d_in[24];
    const float* b_e0 = (const float*)d_in[25];
    const float* g_e1 = (const float*)d_in[26];
    const float* b_e1 = (const float*)d_in[27];
    const float* g_m  = (const float*)d_in[28];
    const float* b_m  = (const float*)d_in[29];
    const float* wsc  = (const float*)d_in[30];
    const int*   src  = (const int*)d_in[31];
    const int*   dst  = (const int*)d_in[32];

    const int N = in_sizes[0] / 96;
    const int E = in_sizes[1] / 32;

    float* ws    = (float*)d_ws;
    float* qkv   = ws;                                      // N*288 f32
    float* agg   = qkv + (size_t)N * 288;                   // N*128 f32
    float* h0    = agg + (size_t)N * 128;                   // N*96 f32
    float* hp    = h0 + (size_t)N * 96;                     // N*96 f32
    unsigned short* v16 = (unsigned short*)(hp + (size_t)N * 96);    // N*96 bf16
    unsigned short* exve16 = v16 + (size_t)N * 96;          // E*64 bf16
    int*   pos   = (int*)(exve16 + (size_t)E * 64);         // E
    int*   srcs  = pos + E;                                 // E
    int*   cnt   = srcs + E;                                // N
    int*   offv  = cnt + N;                                 // N
    int*   cur   = offv + N;                                // N
    float* tbuf  = ws;                                      // N*192, reuses qkv late
    float* hout  = (float*)d_out;
    float* eoutp = (float*)d_out + (size_t)N * 96;

    hipMemsetAsync(cnt, 0, (size_t)N * sizeof(int), stream);

    const int mt = (N + 63) / 64;
    const int et = (E + 255) / 256;

    // CSR bucketing
    count_kernel<<<et, 256, 0, stream>>>(dst, cnt, E);
    scan_kernel<<<1, 1024, 0, stream>>>(cnt, offv, cur, N);
    scatter_kernel<<<et, 256, 0, stream>>>(dst, src, cur, pos, srcs, E);

    // node side: h0 = LN(feat); qkv = h0 @ [Wq|Wk|Wv]  (one MULTI launch)
    ln96_kernel<<<(N + 7) / 8, 256, 0, stream>>>(feat, g_n0, b_n0, h0, N);
    mgemm_kernel<1,0,0><<<dim3(mt, 3), 256, 0, stream>>>(
        h0, 96, Wq, Wk, Wv, 96, bq, bk, bv, nullptr, nullptr,
        qkv, 288, v16, N, 96);

    // fused edge tile pass
    edge_tile_kernel<<<(E + 63) / 64, 256, 0, stream>>>(edge, qkv, src, dst, pos,
                                             We, be, Wb, bb, Wf0, bf0, Wf1, bf1,
                                             g_e0, b_e0, g_e1, b_e1,
                                             exve16, eoutp, E);

    // gather per node -> normalized agg[N,128]
    gather_kernel<<<(N + 3) / 4, 256, 0, stream>>>(exve16, v16, srcs, offv, cnt, agg, N);

    // h_pre = feat*(1+w) + agg @ Wvv + bvv
    mgemm_kernel<0,0,1><<<dim3(mt, 1), 256, 0, stream>>>(
        agg, 128, Wvv, Wvv, Wvv, 96, bvv, bvv, bvv, feat, wsc,
        hp, 96, nullptr, N, 128);
    // hn = LN(h_pre)
    ln96_kernel<<<(N + 7) / 8, 256, 0, stream>>>(hp, g_m, b_m, h0, N);
    // t = relu(hn @ Wm0 + bm0)
    mgemm_kernel<0,1,0><<<dim3(mt, 2), 256, 0, stream>>>(
        h0, 96, Wm0, Wm0, Wm0, 192, bm0, bm0, bm0, nullptr, nullptr,
        tbuf, 192, nullptr, N, 96);
    // h_out = h_pre + t @ Wm1 + bm1
    mgemm_kernel<0,0,1><<<dim3(mt, 1), 256, 0, stream>>>(
        tbuf, 192, Wm1, Wm1, Wm1, 96, bm1, bm1, bm1, hp, nullptr,
        hout, 96, nullptr, N, 192);
}

// Round 13
// 941.511 us; speedup vs baseline: 2.2090x; 1.0086x over previous
//
#include <hip/hip_runtime.h>
#include <cstdint>
#include <cstddef>

// ---------------------------------------------------------------------------
// EGT layer.  N nodes (DIM=96, H=32, HD=3), E edges.
// edge_tile_kernel: 64-edge tile per block, qk in-kernel, MFMA bf16 GEMMs.
// mgemm_kernel: MFMA bf16 node GEMM; LNA mode fuses row-LayerNorm into the
// A-staging (kills ln96 kernels + h0 buffer); A16 reads bf16 A (agg16).
// gather: 2x unrolled (two edges in flight per barrier), writes bf16 agg16.
// CSR-ordered exve so gather reads are contiguous.
// ---------------------------------------------------------------------------

typedef short  s16x8 __attribute__((ext_vector_type(8)));
typedef short  s16x4 __attribute__((ext_vector_type(4)));
typedef float  f32x4 __attribute__((ext_vector_type(4)));

__device__ __forceinline__ unsigned short f2b(float x) {
    union { float f; unsigned u; } v; v.f = x;
    unsigned r = v.u + 0x7FFF + ((v.u >> 16) & 1);   // RNE
    return (unsigned short)(r >> 16);
}
__device__ __forceinline__ float b2f(unsigned short u) {
    union { unsigned u; float f; } v; v.u = ((unsigned)u) << 16; return v.f;
}

// ---------------- MFMA node GEMM ----------------
// C[M, y*96 .. +96] = A[M,K] @ B + bias (+ LN on A if LNA; bf16 A if A16)
// MULTI: y selects B0/B1/B2 (q|k|v); y==2 also writes bf16 C16.
template<int MULTI, int LNA, int A16, int RELU, int RES>
__global__ __launch_bounds__(256) void mgemm_kernel(
    const void* __restrict__ Av, int lda,
    const float* __restrict__ B0, const float* __restrict__ B1,
    const float* __restrict__ B2, int ldb,
    const float* __restrict__ bias0, const float* __restrict__ bias1,
    const float* __restrict__ bias2,
    const float* __restrict__ lng, const float* __restrict__ lnbv,
    const float* __restrict__ resid, const float* __restrict__ wptr,
    float* __restrict__ C, int ldc, unsigned short* __restrict__ C16,
    int M, int K)
{
    __shared__ unsigned short sAL[64 * 200];  // A tile bf16, stride K+8 (max 200)
    __shared__ unsigned short sB[96 * 40];    // B^T chunk bf16 [96][32]

    const int tid = threadIdx.x;
    const int m0 = blockIdx.x * 64;
    const int y  = blockIdx.y;
    const float* B = MULTI ? (y == 0 ? B0 : (y == 1 ? B1 : B2)) : B0;
    const int nbB = MULTI ? 0 : y * 96;
    const int nbC = y * 96;
    const int w = tid >> 6, l = tid & 63, fr = l & 15, kg = l >> 4;
    const int KP = K + 8;

    // ---- stage A tile once ----
    if (LNA) {
        // K == 96: lane owns 24 cols of its row; LN wave-parallel.
        const float* Af = (const float*)Av;
        const int row = 16 * w + fr;
        const int grow = m0 + row;
        float x[24];
        if (grow < M) {
            #pragma unroll
            for (int t = 0; t < 6; t++)
                *(float4*)&x[t * 4] = *(const float4*)(Af + (size_t)grow * lda + 24 * kg + t * 4);
        } else {
            #pragma unroll
            for (int t = 0; t < 24; t++) x[t] = 0.f;
        }
        float s = 0.f;
        #pragma unroll
        for (int t = 0; t < 24; t++) s += x[t];
        s += __shfl_xor(s, 16, 64); s += __shfl_xor(s, 32, 64);
        float mu = s * (1.f / 96.f);
        float v2 = 0.f;
        #pragma unroll
        for (int t = 0; t < 24; t++) { float d = x[t] - mu; v2 += d * d; }
        v2 += __shfl_xor(v2, 16, 64); v2 += __shfl_xor(v2, 32, 64);
        float rs = rsqrtf(v2 * (1.f / 96.f) + 1e-5f);
        #pragma unroll
        for (int t3 = 0; t3 < 3; t3++) {
            s16x8 yv;
            #pragma unroll
            for (int u = 0; u < 8; u++) {
                int cidx = 24 * kg + t3 * 8 + u;
                yv[u] = (short)f2b((x[t3 * 8 + u] - mu) * rs * lng[cidx] + lnbv[cidx]);
            }
            *(s16x8*)&sAL[row * KP + 24 * kg + t3 * 8] = yv;
        }
    } else {
        const int nseg = K >> 3;
        for (int idx = tid; idx < 64 * nseg; idx += 256) {
            int row = idx / nseg, k8 = (idx - row * nseg) * 8;
            int grow = m0 + row;
            s16x8 a8 = (s16x8){0, 0, 0, 0, 0, 0, 0, 0};
            if (grow < M) {
                if (A16) {
                    a8 = *(const s16x8*)((const unsigned short*)Av + (size_t)grow * lda + k8);
                } else {
                    const float* Af = (const float*)Av;
                    float4 v0 = *(const float4*)(Af + (size_t)grow * lda + k8);
                    float4 v1 = *(const float4*)(Af + (size_t)grow * lda + k8 + 4);
                    a8[0] = (short)f2b(v0.x); a8[1] = (short)f2b(v0.y);
                    a8[2] = (short)f2b(v0.z); a8[3] = (short)f2b(v0.w);
                    a8[4] = (short)f2b(v1.x); a8[5] = (short)f2b(v1.y);
                    a8[6] = (short)f2b(v1.z); a8[7] = (short)f2b(v1.w);
                }
            }
            *(s16x8*)&sAL[row * KP + k8] = a8;
        }
    }

    f32x4 acc[6];
    #pragma unroll
    for (int i = 0; i < 6; i++) acc[i] = (f32x4){0.f, 0.f, 0.f, 0.f};

    for (int kc = 0; kc < K; kc += 32) {
        #pragma unroll
        for (int r = 0; r < 3; r++) {
            int idx = tid + 256 * r;
            int k = idx / 24, n4 = (idx - k * 24) * 4;
            float4 v = *(const float4*)(B + (size_t)(kc + k) * ldb + nbB + n4);
            sB[(n4 + 0) * 40 + k] = f2b(v.x);
            sB[(n4 + 1) * 40 + k] = f2b(v.y);
            sB[(n4 + 2) * 40 + k] = f2b(v.z);
            sB[(n4 + 3) * 40 + k] = f2b(v.w);
        }
        __syncthreads();
        {
            s16x8 a = *(s16x8*)&sAL[(16 * w + fr) * KP + kc + kg * 8];
            #pragma unroll
            for (int nt = 0; nt < 6; nt++) {
                s16x8 b = *(s16x8*)&sB[(16 * nt + fr) * 40 + kg * 8];
                acc[nt] = __builtin_amdgcn_mfma_f32_16x16x32_bf16(a, b, acc[nt], 0, 0, 0);
            }
        }
        __syncthreads();
    }

    float scale = 1.f;
    if (RES) scale = wptr ? (1.f + wptr[0]) : 1.f;
    const float* biasp = MULTI ? (y == 0 ? bias0 : (y == 1 ? bias1 : bias2)) : bias0;
    const int bbase = MULTI ? 0 : nbB;

    #pragma unroll
    for (int nt = 0; nt < 6; nt++) {
        int cl = nt * 16 + fr;
        float bv = biasp[bbase + cl];
        int gcol = nbC + cl;
        #pragma unroll
        for (int r = 0; r < 4; r++) {
            int row = m0 + 16 * w + 4 * kg + r;
            if (row >= M) continue;
            float v = acc[nt][r] + bv;
            if (RELU) v = fmaxf(v, 0.f);
            if (RES) v += scale * resid[(size_t)row * ldc + gcol];
            C[(size_t)row * ldc + gcol] = v;
            if (MULTI && C16 != nullptr && y == 2)
                C16[(size_t)row * 96 + cl] = f2b(v);
        }
    }
}

// ---------------- CSR bucketing ----------------
__global__ __launch_bounds__(256) void count_kernel(
    const int* __restrict__ dst, int* __restrict__ cnt, int E)
{
    int i = blockIdx.x * 256 + threadIdx.x;
    if (i < E) atomicAdd(&cnt[dst[i]], 1);
}

__global__ __launch_bounds__(1024) void scan_kernel(
    const int* __restrict__ cnt, int* __restrict__ off, int* __restrict__ cur, int N)
{
    __shared__ int s[1024];
    const int tid = threadIdx.x;
    const int chunk = (N + 1023) >> 10;
    const int lo = tid * chunk;
    const int hi = min(lo + chunk, N);
    int sum = 0;
    for (int i = lo; i < hi; i++) sum += cnt[i];
    s[tid] = sum;
    __syncthreads();
    for (int d = 1; d < 1024; d <<= 1) {
        int v = (tid >= d) ? s[tid - d] : 0;
        __syncthreads();
        s[tid] += v;
        __syncthreads();
    }
    int base = (tid == 0) ? 0 : s[tid - 1];
    for (int i = lo; i < hi; i++) {
        off[i] = base; cur[i] = base;
        base += cnt[i];
    }
}

__global__ __launch_bounds__(256) void scatter_kernel(
    const int* __restrict__ dst, const int* __restrict__ src,
    int* __restrict__ cur, int* __restrict__ pos, int* __restrict__ srcs, int E)
{
    int i = blockIdx.x * 256 + threadIdx.x;
    if (i < E) {
        int p = atomicAdd(&cur[dst[i]], 1);
        pos[i] = p;
        srcs[p] = src[i];
    }
}

// ---------------- edge tile kernel: 64 edges per block, MFMA GEMMs ----------
__global__ __launch_bounds__(256, 4) void edge_tile_kernel(
    const float* __restrict__ edge, const float* __restrict__ qkv,
    const int* __restrict__ src, const int* __restrict__ dst,
    const int* __restrict__ pos,
    const float* __restrict__ We, const float* __restrict__ be,
    const float* __restrict__ Wb, const float* __restrict__ bb,
    const float* __restrict__ Wf0, const float* __restrict__ bf0,
    const float* __restrict__ Wf1, const float* __restrict__ bf1,
    const float* __restrict__ ge0, const float* __restrict__ be0,
    const float* __restrict__ ge1, const float* __restrict__ be1,
    unsigned short* __restrict__ exve16, float* __restrict__ eout, int E)
{
    __shared__ float          sEV[64 * 36];
    __shared__ unsigned short sQK[64 * 40];
    __shared__ unsigned short sA [64 * 40];
    __shared__ unsigned short sB [64 * 40];
    __shared__ unsigned short sB2[32 * 72];
    __shared__ unsigned short sX [64 * 72];

    const int tid = threadIdx.x;
    const long long e0 = (long long)blockIdx.x * 64;
    const int w  = tid >> 6;
    const int l  = tid & 63;
    const int fr = l & 15;
    const int kg = l >> 4;

    // ---- S1a: fused score: 4 threads/edge, 8 heads each ----
    {
        const int row = tid >> 2;
        const int j   = tid & 3;
        long long e = e0 + row;
        float q[24], k[24];
        if (e < E) {
            int dn = dst[e], sn = src[e];
            const float* qp = qkv + (size_t)dn * 288 + 24 * j;
            const float* kp = qkv + (size_t)sn * 288 + 96 + 24 * j;
            #pragma unroll
            for (int t = 0; t < 6; t++) {
                *(float4*)&q[t * 4] = *(const float4*)(qp + t * 4);
                *(float4*)&k[t * 4] = *(const float4*)(kp + t * 4);
            }
        } else {
            #pragma unroll
            for (int t = 0; t < 24; t++) { q[t] = 0.f; k[t] = 0.f; }
        }
        s16x8 qkb;
        #pragma unroll
        for (int t = 0; t < 8; t++) {
            float d = k[3*t]*q[3*t] + k[3*t+1]*q[3*t+1] + k[3*t+2]*q[3*t+2];
            qkb[t] = (short)f2b(0.5f * d);
        }
        *(s16x8*)&sQK[row * 40 + 8 * j] = qkb;
    }

    // ---- S1b: stage ev (f32), Wb|We^T (bf16), Wf1^T (bf16) ----
    #pragma unroll
    for (int rr = 0; rr < 2; rr++) {
        int idx = tid + 256 * rr;
        int row = idx >> 3, c4 = (idx & 7) * 4;
        long long e = e0 + row;
        float4 v = make_float4(0.f, 0.f, 0.f, 0.f);
        if (e < E) v = *(const float4*)(edge + e * 32 + c4);
        *(float4*)&sEV[row * 36 + c4] = v;
    }
    {
        int k = tid >> 3, c4 = (tid & 7) * 4;
        float4 vb = *(const float4*)(Wb + k * 32 + c4);
        float4 ve = *(const float4*)(We + k * 32 + c4);
        sB[(c4 + 0) * 40 + k] = f2b(vb.x); sB[(c4 + 1) * 40 + k] = f2b(vb.y);
        sB[(c4 + 2) * 40 + k] = f2b(vb.z); sB[(c4 + 3) * 40 + k] = f2b(vb.w);
        sB[(32 + c4 + 0) * 40 + k] = f2b(ve.x); sB[(32 + c4 + 1) * 40 + k] = f2b(ve.y);
        sB[(32 + c4 + 2) * 40 + k] = f2b(ve.z); sB[(32 + c4 + 3) * 40 + k] = f2b(ve.w);
    }
    #pragma unroll
    for (int rr = 0; rr < 2; rr++) {
        int idx = tid + 256 * rr;
        int k = idx >> 3, c4 = (idx & 7) * 4;
        float4 v = *(const float4*)(Wf1 + k * 32 + c4);
        sB2[(c4 + 0) * 72 + k] = f2b(v.x); sB2[(c4 + 1) * 72 + k] = f2b(v.y);
        sB2[(c4 + 2) * 72 + k] = f2b(v.z); sB2[(c4 + 3) * 72 + k] = f2b(v.w);
    }
    __syncthreads();

    // ---- S2: LN1 -> ew rows (bf16) in sA ----
    {
        const int row = 16 * w + (tid & 15);
        const int q = (tid & 63) >> 4;
        float x[8];
        *(float4*)&x[0] = *(float4*)&sEV[row * 36 + 8 * q];
        *(float4*)&x[4] = *(float4*)&sEV[row * 36 + 8 * q + 4];
        float s = x[0] + x[1] + x[2] + x[3] + x[4] + x[5] + x[6] + x[7];
        s += __shfl_xor(s, 16, 64); s += __shfl_xor(s, 32, 64);
        float mu = s * (1.f / 32.f);
        float v2 = 0.f;
        #pragma unroll
        for (int i = 0; i < 8; i++) { float d = x[i] - mu; v2 += d * d; }
        v2 += __shfl_xor(v2, 16, 64); v2 += __shfl_xor(v2, 32, 64);
        float rs = rsqrtf(v2 * (1.f / 32.f) + 1e-5f);
        float4 g1 = *(const float4*)(ge0 + 8 * q), g2 = *(const float4*)(ge0 + 8 * q + 4);
        float4 b1 = *(const float4*)(be0 + 8 * q), b2 = *(const float4*)(be0 + 8 * q + 4);
        float gg[8] = {g1.x, g1.y, g1.z, g1.w, g2.x, g2.y, g2.z, g2.w};
        float bs[8] = {b1.x, b1.y, b1.z, b1.w, b2.x, b2.y, b2.z, b2.w};
        s16x8 y;
        #pragma unroll
        for (int i = 0; i < 8; i++)
            y[i] = (short)f2b((x[i] - mu) * rs * gg[i] + bs[i]);
        *(s16x8*)&sA[row * 40 + 8 * q] = y;
    }
    __syncthreads();

    // ---- S3: GEMM1 (MFMA)  [64][64 = sc|veh] = ew @ [Wb|We] ----
    f32x4 acc[4];
    {
        s16x8 a = *(s16x8*)&sA[(16 * w + fr) * 40 + kg * 8];
        #pragma unroll
        for (int nt = 0; nt < 4; nt++) {
            s16x8 b = *(s16x8*)&sB[(16 * nt + fr) * 40 + kg * 8];
            f32x4 z = {0.f, 0.f, 0.f, 0.f};
            acc[nt] = __builtin_amdgcn_mfma_f32_16x16x32_bf16(a, b, z, 0, 0, 0);
        }
    }
    __syncthreads();

    // ---- S4: epilogue1 (exp -> sX; er -> sEV) + restage Wf0 -> sB ----
    #pragma unroll
    for (int nt = 0; nt < 2; nt++) {
        int col = nt * 16 + fr;
        float bbv = bb[col];
        #pragma unroll
        for (int r = 0; r < 4; r++) {
            int row = 16 * w + 4 * kg + r;
            float sc = acc[nt][r] + b2f(sQK[row * 40 + col]) + bbv;
            sX[row * 72 + col] = f2b(__expf(sc));
            float er = sc + sEV[row * 36 + col];
            sEV[row * 36 + col] = er;
        }
    }
    #pragma unroll
    for (int nt = 2; nt < 4; nt++) {
        int col = (nt - 2) * 16 + fr;
        float bev = be[col];
        #pragma unroll
        for (int r = 0; r < 4; r++) {
            int row = 16 * w + 4 * kg + r;
            sX[row * 72 + 32 + col] = f2b(acc[nt][r] + bev);
        }
    }
    #pragma unroll
    for (int rr = 0; rr < 2; rr++) {
        int idx = tid + 256 * rr;
        int k = idx >> 4, c4 = (idx & 15) * 4;
        float4 v = *(const float4*)(Wf0 + k * 64 + c4);
        sB[(c4 + 0) * 40 + k] = f2b(v.x); sB[(c4 + 1) * 40 + k] = f2b(v.y);
        sB[(c4 + 2) * 40 + k] = f2b(v.z); sB[(c4 + 3) * 40 + k] = f2b(v.w);
    }
    __syncthreads();

    // ---- S5: copy sX -> exve16 at CSR slot ; LN2 (er -> en bf16 in sA) ----
    #pragma unroll
    for (int rr = 0; rr < 2; rr++) {
        int idx = tid + 256 * rr;
        int row = idx >> 3, c8 = (idx & 7) * 8;
        long long e = e0 + row;
        if (e < E) {
            int p = pos[e];
            *(s16x8*)(exve16 + (size_t)p * 64 + c8) = *(s16x8*)&sX[row * 72 + c8];
        }
    }
    {
        const int row = 16 * w + (tid & 15);
        const int q = (tid & 63) >> 4;
        float x[8];
        *(float4*)&x[0] = *(float4*)&sEV[row * 36 + 8 * q];
        *(float4*)&x[4] = *(float4*)&sEV[row * 36 + 8 * q + 4];
        float s = x[0] + x[1] + x[2] + x[3] + x[4] + x[5] + x[6] + x[7];
        s += __shfl_xor(s, 16, 64); s += __shfl_xor(s, 32, 64);
        float mu = s * (1.f / 32.f);
        float v2 = 0.f;
        #pragma unroll
        for (int i = 0; i < 8; i++) { float d = x[i] - mu; v2 += d * d; }
        v2 += __shfl_xor(v2, 16, 64); v2 += __shfl_xor(v2, 32, 64);
        float rs = rsqrtf(v2 * (1.f / 32.f) + 1e-5f);
        float4 g1 = *(const float4*)(ge1 + 8 * q), g2 = *(const float4*)(ge1 + 8 * q + 4);
        float4 b1 = *(const float4*)(be1 + 8 * q), b2 = *(const float4*)(be1 + 8 * q + 4);
        float gg[8] = {g1.x, g1.y, g1.z, g1.w, g2.x, g2.y, g2.z, g2.w};
        float bs[8] = {b1.x, b1.y, b1.z, b1.w, b2.x, b2.y, b2.z, b2.w};
        s16x8 y;
        #pragma unroll
        for (int i = 0; i < 8; i++)
            y[i] = (short)f2b((x[i] - mu) * rs * gg[i] + bs[i]);
        *(s16x8*)&sA[row * 40 + 8 * q] = y;
    }
    __syncthreads();

    // ---- S6: GEMM2 (MFMA)  F[64][64] = relu(en @ Wf0 + bf0) -> sX rows ----
    {
        s16x8 a = *(s16x8*)&sA[(16 * w + fr) * 40 + kg * 8];
        #pragma unroll
        for (int nt = 0; nt < 4; nt++) {
            s16x8 b = *(s16x8*)&sB[(16 * nt + fr) * 40 + kg * 8];
            f32x4 z = {0.f, 0.f, 0.f, 0.f};
            f32x4 a2 = __builtin_amdgcn_mfma_f32_16x16x32_bf16(a, b, z, 0, 0, 0);
            int col = nt * 16 + fr;
            float b0v = bf0[col];
            #pragma unroll
            for (int r = 0; r < 4; r++) {
                int row = 16 * w + 4 * kg + r;
                sX[row * 72 + col] = f2b(fmaxf(a2[r] + b0v, 0.f));
            }
        }
    }
    __syncthreads();

    // ---- S7: GEMM3 (MFMA)  out[64][32] = F @ Wf1 + er + bf1 -> sEV ----
    {
        s16x8 a0 = *(s16x8*)&sX[(16 * w + fr) * 72 + kg * 8];
        s16x8 a1 = *(s16x8*)&sX[(16 * w + fr) * 72 + 32 + kg * 8];
        #pragma unroll
        for (int nt = 0; nt < 2; nt++) {
            s16x8 b0 = *(s16x8*)&sB2[(16 * nt + fr) * 72 + kg * 8];
            s16x8 b1 = *(s16x8*)&sB2[(16 * nt + fr) * 72 + 32 + kg * 8];
            f32x4 z = {0.f, 0.f, 0.f, 0.f};
            f32x4 t = __builtin_amdgcn_mfma_f32_16x16x32_bf16(a0, b0, z, 0, 0, 0);
            t = __builtin_amdgcn_mfma_f32_16x16x32_bf16(a1, b1, t, 0, 0, 0);
            int col = nt * 16 + fr;
            float bf1v = bf1[col];
            #pragma unroll
            for (int r = 0; r < 4; r++) {
                int row = 16 * w + 4 * kg + r;
                float out = t[r] + sEV[row * 36 + col] + bf1v;
                sEV[row * 36 + col] = out;
            }
        }
    }
    __syncthreads();

    // ---- S8: copy sEV[:, 0..32) -> eout ----
    #pragma unroll
    for (int rr = 0; rr < 2; rr++) {
        int idx = tid + 256 * rr;
        int row = idx >> 3, c4 = (idx & 7) * 4;
        long long e = e0 + row;
        if (e < E)
            *(float4*)(eout + e * 32 + c4) = *(float4*)&sEV[row * 36 + c4];
    }
}

// ---------------- gather: wave/node, 2 edges in flight per half ------------
__global__ __launch_bounds__(256) void gather_kernel(
    const unsigned short* __restrict__ exve16, const unsigned short* __restrict__ v16,
    const int* __restrict__ srcs, const int* __restrict__ off,
    const int* __restrict__ cnt, unsigned short* __restrict__ agg16, int N)
{
    __shared__ unsigned short sV16[4][2][2][96];
    __shared__ unsigned short sE16[4][2][2][64];
    const int wave = threadIdx.x >> 6;
    const int lane = threadIdx.x & 63;
    const int head = lane & 31;
    const int half = lane >> 5;
    int n = blockIdx.x * 4 + wave;
    if (n >= N) return;
    const int o = off[n], d = cnt[n];
    float a0 = 0.f, a1 = 0.f, a2 = 0.f, a3 = 0.f, den = 0.f;
    for (int i = half; i < d; i += 4) {
        const int i2 = i + 2;
        {
            int sn = srcs[o + i];
            const unsigned short* vr = v16 + (size_t)sn * 96;
            const unsigned short* er = exve16 + (size_t)(o + i) * 64;
            if (head < 12)
                *(s16x8*)&sV16[wave][half][0][head * 8] = *(const s16x8*)(vr + head * 8);
            else if (head >= 24)
                *(s16x8*)&sE16[wave][half][0][(head - 24) * 8] = *(const s16x8*)(er + (head - 24) * 8);
        }
        if (i2 < d) {
            int sn = srcs[o + i2];
            const unsigned short* vr = v16 + (size_t)sn * 96;
            const unsigned short* er = exve16 + (size_t)(o + i2) * 64;
            if (head < 12)
                *(s16x8*)&sV16[wave][half][1][head * 8] = *(const s16x8*)(vr + head * 8);
            else if (head >= 24)
                *(s16x8*)&sE16[wave][half][1][(head - 24) * 8] = *(const s16x8*)(er + (head - 24) * 8);
        }
        __builtin_amdgcn_wave_barrier();
        {
            float ex = b2f(sE16[wave][half][0][head]);
            float vv = b2f(sE16[wave][half][0][32 + head]);
            a0 += ex * b2f(sV16[wave][half][0][head * 3]);
            a1 += ex * b2f(sV16[wave][half][0][head * 3 + 1]);
            a2 += ex * b2f(sV16[wave][half][0][head * 3 + 2]);
            a3 += ex * vv;
            den += ex;
        }
        if (i2 < d) {
            float ex = b2f(sE16[wave][half][1][head]);
            float vv = b2f(sE16[wave][half][1][32 + head]);
            a0 += ex * b2f(sV16[wave][half][1][head * 3]);
            a1 += ex * b2f(sV16[wave][half][1][head * 3 + 1]);
            a2 += ex * b2f(sV16[wave][half][1][head * 3 + 2]);
            a3 += ex * vv;
            den += ex;
        }
        __builtin_amdgcn_wave_barrier();
    }
    a0 += __shfl_xor(a0, 32, 64);
    a1 += __shfl_xor(a1, 32, 64);
    a2 += __shfl_xor(a2, 32, 64);
    a3 += __shfl_xor(a3, 32, 64);
    den += __shfl_xor(den, 32, 64);
    if (half == 0) {
        float sc = (d > 0) ? 1.f / den : 0.f;
        s16x4 ov;
        ov[0] = (short)f2b(a0 * sc);
        ov[1] = (short)f2b(a1 * sc);
        ov[2] = (short)f2b(a2 * sc);
        ov[3] = (short)f2b(a3 * sc);
        *(s16x4*)(agg16 + (size_t)n * 128 + head * 4) = ov;
    }
}

// ---------------------------------------------------------------------------
extern "C" void kernel_launch(void* const* d_in, const int* in_sizes, int n_in,
                              void* d_out, int out_size, void* d_ws, size_t ws_size,
                              hipStream_t stream)
{
    (void)n_in; (void)out_size; (void)ws_size;
    const float* feat = (const float*)d_in[0];
    const float* edge = (const float*)d_in[1];
    const float* Wq   = (const float*)d_in[2];
    const float* bq   = (const float*)d_in[3];
    const float* Wk   = (const float*)d_in[4];
    const float* bk   = (const float*)d_in[5];
    const float* Wv   = (const float*)d_in[6];
    const float* bv   = (const float*)d_in[7];
    const float* We   = (const float*)d_in[8];
    const float* be   = (const float*)d_in[9];
    const float* Wb   = (const float*)d_in[10];
    const float* bb   = (const float*)d_in[11];
    const float* Wvv  = (const float*)d_in[12];
    const float* bvv  = (const float*)d_in[13];
    const float* Wf0  = (const float*)d_in[14];
    const float* bf0  = (const float*)d_in[15];
    const float* Wf1  = (const float*)d_in[16];
    const float* bf1  = (const float*)d_in[17];
    const float* Wm0  = (const float*)d_in[18];
    const float* bm0  = (const float*)d_in[19];
    const float* Wm1  = (const float*)d_in[20];
    const float* bm1  = (const float*)d_in[21];
    const float* g_n0 = (const float*)d_in[22];
    const float* b_n0 = (const float*)d_in[23];
    const float* g_e0 = (const float*)d_in[24];
    const float* b_e0 = (const float*)d_in[25];
    const float* g_e1 = (const float*)d_in[26];
    const float* b_e1 = (const float*)d_in[27];
    const float* g_m  = (const float*)d_in[28];
    const float* b_m  = (const float*)d_in[29];
    const float* wsc  = (const float*)d_in[30];
    const int*   src  = (const int*)d_in[31];
    const int*   dst  = (const int*)d_in[32];

    const int N = in_sizes[0] / 96;
    const int E = in_sizes[1] / 32;

    float* ws    = (float*)d_ws;
    float* qkv   = ws;                                      // N*288 f32
    float* hp    = qkv + (size_t)N * 288;                   // N*96 f32
    unsigned short* agg16 = (unsigned short*)(hp + (size_t)N * 96);  // N*128 bf16
    unsigned short* v16   = agg16 + (size_t)N * 128;        // N*96 bf16
    unsigned short* exve16 = v16 + (size_t)N * 96;          // E*64 bf16
    int*   pos   = (int*)(exve16 + (size_t)E * 64);         // E
    int*   srcs  = pos + E;                                 // E
    int*   cnt   = srcs + E;                                // N
    int*   offv  = cnt + N;                                 // N
    int*   cur   = offv + N;                                // N
    float* tbuf  = ws;                                      // N*192, over dead qkv
    float* hout  = (float*)d_out;
    float* eoutp = (float*)d_out + (size_t)N * 96;

    hipMemsetAsync(cnt, 0, (size_t)N * sizeof(int), stream);

    const int mt = (N + 63) / 64;
    const int et = (E + 255) / 256;

    // CSR bucketing
    count_kernel<<<et, 256, 0, stream>>>(dst, cnt, E);
    scan_kernel<<<1, 1024, 0, stream>>>(cnt, offv, cur, N);
    scatter_kernel<<<et, 256, 0, stream>>>(dst, src, cur, pos, srcs, E);

    // qkv = LN(feat) @ [Wq|Wk|Wv]  (LN fused; y==2 also emits bf16 v16)
    mgemm_kernel<1,1,0,0,0><<<dim3(mt, 3), 256, 0, stream>>>(
        feat, 96, Wq, Wk, Wv, 96, bq, bk, bv, g_n0, b_n0,
        nullptr, nullptr, qkv, 288, v16, N, 96);

    // fused edge tile pass
    edge_tile_kernel<<<(E + 63) / 64, 256, 0, stream>>>(edge, qkv, src, dst, pos,
                                             We, be, Wb, bb, Wf0, bf0, Wf1, bf1,
                                             g_e0, b_e0, g_e1, b_e1,
                                             exve16, eoutp, E);

    // gather per node -> normalized agg16[N,128] (bf16)
    gather_kernel<<<(N + 3) / 4, 256, 0, stream>>>(exve16, v16, srcs, offv, cnt, agg16, N);

    // h_pre = feat*(1+w) + agg @ Wvv + bvv   (bf16 A)
    mgemm_kernel<0,0,1,0,1><<<dim3(mt, 1), 256, 0, stream>>>(
        agg16, 128, Wvv, Wvv, Wvv, 96, bvv, bvv, bvv, nullptr, nullptr,
        feat, wsc, hp, 96, nullptr, N, 128);
    // t = relu(LN(hp) @ Wm0 + bm0)   (LN fused)
    mgemm_kernel<0,1,0,1,0><<<dim3(mt, 2), 256, 0, stream>>>(
        hp, 96, Wm0, Wm0, Wm0, 192, bm0, bm0, bm0, g_m, b_m,
        nullptr, nullptr, tbuf, 192, nullptr, N, 96);
    // h_out = hp + t @ Wm1 + bm1
    mgemm_kernel<0,0,0,0,1><<<dim3(mt, 1), 256, 0, stream>>>(
        tbuf, 192, Wm1, Wm1, Wm1, 96, bm1, bm1, bm1, nullptr, nullptr,
        hp, nullptr, hout, 96, nullptr, N, 192);
}